// Round 2
// baseline (498.149 us; speedup 1.0000x reference)
//
#include <hip/hip_runtime.h>
#include <hip/hip_bf16.h>

// ---------------------------------------------------------------------------
// MoE (top-2 of 8 experts), B=4 T=2048 C=1024 H=2048 E=8. FP32 in/out
// (reference dtype); internal GEMMs in bf16 MFMA (error << 2% threshold).
// Pipeline: gate(fp32) -> route -> cvt x->bf16 -> pack weights fp32->bf16
//           transposed -> grouped GEMM1 (x@Wfc, silu, *gate_w) ->
//           grouped GEMM2 (h@Wproj) -> combine 2 slots per token (fp32 out).
// GEMM structure = m97 ladder: 128x128 tile, BK=32, global_load_lds width=16,
// XOR-swizzled LDS, mfma_f32_16x16x32_bf16, 4 waves x 4x4 accumulators.
// ---------------------------------------------------------------------------

#define NTOK 8192
#define CD   1024
#define HD   2048
#define NE   8
#define NSLOT 16384   // NTOK * top_k
#define MTILES 32     // supports up to 4096 tokens per expert (mean 2048)

typedef short  short8_t  __attribute__((ext_vector_type(8)));
typedef __bf16 bf16x8_t  __attribute__((ext_vector_type(8)));
typedef float  f32x4_t   __attribute__((ext_vector_type(4)));

// MFMA builtin arg-type shim: satisfies either V8s or V8bf16 signatures.
struct FragArg {
  short8_t v;
  __device__ operator short8_t() const { return v; }
  __device__ operator bf16x8_t() const { return __builtin_bit_cast(bf16x8_t, v); }
};

static __device__ __forceinline__ float b2f(unsigned short u) {
  union { float f; unsigned int i; } w; w.i = ((unsigned int)u) << 16; return w.f;
}
static __device__ __forceinline__ unsigned short f2b(float f) {
  unsigned int u = __float_as_uint(f);
  u += 0x7fffu + ((u >> 16) & 1u);           // round-to-nearest-even
  return (unsigned short)(u >> 16);
}
static __device__ __forceinline__ void gl2lds16(const void* g, void* l) {
  __builtin_amdgcn_global_load_lds((__attribute__((address_space(1))) void*)g,
                                   (__attribute__((address_space(3))) void*)l,
                                   16, 0, 0);
}
// XOR swizzle: 16B-chunk slot for (row, k-chunk) so 16-lane fragment reads are
// 2-way (free) on the 32 banks. f(row) = (row>>1)&3.
static __device__ __forceinline__ int swz(int row, int kc) {
  return row * 4 + (kc ^ ((row >> 1) & 3));
}

// --------------------------- gating (fp32) ---------------------------------
__global__ __launch_bounds__(256) void gate_kernel(
    const float* __restrict__ x, const float* __restrict__ wg,
    int* __restrict__ tok_e, float* __restrict__ tok_v)
{
  int wv = threadIdx.x >> 6, lane = threadIdx.x & 63;
  int tk = blockIdx.x * 4 + wv;               // one wave per token
  const float* xr = x + (size_t)tk * CD;
  float acc[NE] = {0, 0, 0, 0, 0, 0, 0, 0};
  #pragma unroll
  for (int jj = 0; jj < 4; ++jj) {
    int c0 = (lane + 64 * jj) * 4;            // 4 channels per float4
    float4 xv = *(const float4*)(xr + c0);
    #pragma unroll
    for (int j = 0; j < 4; ++j) {
      float xf = (j == 0) ? xv.x : (j == 1) ? xv.y : (j == 2) ? xv.z : xv.w;
      const float* wr = wg + (size_t)(c0 + j) * NE;
      float4 w0 = *(const float4*)wr;
      float4 w1 = *(const float4*)(wr + 4);
      acc[0] += xf * w0.x; acc[1] += xf * w0.y;
      acc[2] += xf * w0.z; acc[3] += xf * w0.w;
      acc[4] += xf * w1.x; acc[5] += xf * w1.y;
      acc[6] += xf * w1.z; acc[7] += xf * w1.w;
    }
  }
  #pragma unroll
  for (int off = 32; off >= 1; off >>= 1)
    #pragma unroll
    for (int e = 0; e < NE; ++e) acc[e] += __shfl_down(acc[e], off, 64);
  if (lane == 0) {
    float v1 = -3.0e38f, v2 = -3.0e38f; int i1 = 0, i2 = 1;
    #pragma unroll
    for (int e = 0; e < NE; ++e) {            // strict '>' => ties keep lower idx
      float g = acc[e];
      if (g > v1) { v2 = v1; i2 = i1; v1 = g; i1 = e; }
      else if (g > v2) { v2 = g; i2 = e; }
    }
    tok_e[tk * 2] = i1; tok_e[tk * 2 + 1] = i2;
    tok_v[tk * 2] = v1; tok_v[tk * 2 + 1] = v2;
  }
}

// --------------------------- router (1 block) ------------------------------
__global__ __launch_bounds__(256) void router_kernel(
    const int* __restrict__ tok_e, const float* __restrict__ tok_v,
    int* __restrict__ g_counts, int* __restrict__ g_base,
    int* __restrict__ bucket_tok, float* __restrict__ bucket_v,
    int* __restrict__ slot_of)
{
  __shared__ int cnt[NE], bas[NE], cur[NE];
  int t = threadIdx.x;
  if (t < NE) { cnt[t] = 0; cur[t] = 0; }
  __syncthreads();
  for (int s = t; s < NSLOT; s += 256) atomicAdd(&cnt[tok_e[s]], 1);
  __syncthreads();
  if (t == 0) { int o = 0; for (int e = 0; e < NE; ++e) { bas[e] = o; o += cnt[e]; } }
  __syncthreads();
  if (t < NE) { g_counts[t] = cnt[t]; g_base[t] = bas[t]; }
  for (int s = t; s < NSLOT; s += 256) {
    int e = tok_e[s];
    int pos = atomicAdd(&cur[e], 1);
    int sl = bas[e] + pos;
    bucket_tok[sl] = s >> 1;     // token id
    bucket_v[sl]   = tok_v[s];   // raw gate logit = combine weight
    slot_of[s]     = sl;
  }
}

// ----------------------- x fp32 -> bf16 (contiguous) -----------------------
__global__ __launch_bounds__(256) void cvt_x_kernel(
    const float* __restrict__ x, unsigned short* __restrict__ xb)
{
  int gid = blockIdx.x * 256 + threadIdx.x;   // 8 elems per thread
  const float* p = x + (size_t)gid * 8;
  float4 a = *(const float4*)p;
  float4 b = *(const float4*)(p + 4);
  short8_t o;
  o[0] = (short)f2b(a.x); o[1] = (short)f2b(a.y);
  o[2] = (short)f2b(a.z); o[3] = (short)f2b(a.w);
  o[4] = (short)f2b(b.x); o[5] = (short)f2b(b.y);
  o[6] = (short)f2b(b.z); o[7] = (short)f2b(b.w);
  *(short8_t*)(xb + (size_t)gid * 8) = o;
}

// -------------- weight pack: fp32 (D0,D1,8) -> bf16 (8,D1,D0) --------------
__global__ __launch_bounds__(256) void pack_kernel(
    const float* __restrict__ in, unsigned short* __restrict__ out,
    int D0, int D1)
{
  __shared__ __align__(16) unsigned short lds[NE * 32 * 40]; // stride 40, 16B ok
  int b1 = blockIdx.x * 32, b0 = blockIdx.y * 32;
  int t = threadIdx.x;
  int d1i = t & 31, d0q = t >> 5;
  #pragma unroll
  for (int r = 0; r < 4; ++r) {
    int d0i = d0q * 4 + r;
    const float* src = in + ((size_t)(b0 + d0i) * D1 + (b1 + d1i)) * NE;
    float4 v0 = *(const float4*)src;
    float4 v1 = *(const float4*)(src + 4);
    unsigned short* dst0 = &lds[0 * 32 * 40 + d1i * 40 + d0i];
    dst0[0 * 32 * 40] = f2b(v0.x);
    dst0[1 * 32 * 40] = f2b(v0.y);
    dst0[2 * 32 * 40] = f2b(v0.z);
    dst0[3 * 32 * 40] = f2b(v0.w);
    dst0[4 * 32 * 40] = f2b(v1.x);
    dst0[5 * 32 * 40] = f2b(v1.y);
    dst0[6 * 32 * 40] = f2b(v1.z);
    dst0[7 * 32 * 40] = f2b(v1.w);
  }
  __syncthreads();
  int dchunk = t & 3, d1w = (t >> 2) & 31, ehalf = t >> 7;
  #pragma unroll
  for (int p = 0; p < 4; ++p) {
    int e = ehalf + 2 * p;
    short8_t v = *(const short8_t*)&lds[e * 32 * 40 + d1w * 40 + dchunk * 8];
    *(short8_t*)(out + ((size_t)e * D1 + (b1 + d1w)) * D0 + b0 + dchunk * 8) = v;
  }
}

// ------------------- GEMM1: h = v * silu(x_rows @ WfcT) --------------------
__global__ __launch_bounds__(256) void gemm1_kernel(
    const unsigned short* __restrict__ xb, const unsigned short* __restrict__ wfcp,
    const int* __restrict__ g_counts, const int* __restrict__ g_base,
    const int* __restrict__ bucket_tok, const float* __restrict__ bucket_v,
    unsigned short* __restrict__ hbuf)
{
  int e = blockIdx.z, mt = blockIdx.y, nt = blockIdx.x;
  int cnt = g_counts[e];
  int m0 = mt * 128;
  if (m0 >= cnt) return;
  int base = g_base[e];
  int n0 = nt * 128;

  __shared__ __align__(16) unsigned short lsA[128 * 32];
  __shared__ __align__(16) unsigned short lsB[128 * 32];
  __shared__ int   s_tok[128];
  __shared__ float s_v[128];

  int t = threadIdx.x;
  if (t < 128) {
    int ok = (m0 + t) < cnt;
    s_tok[t] = ok ? bucket_tok[base + m0 + t] : 0;
    s_v[t]   = ok ? bucket_v[base + m0 + t] : 0.0f;
  }
  __syncthreads();

  int slot = t & 3;
  int r0 = t >> 2, r1 = r0 + 64;              // each thread stages 2 rows x 16B
  int gc0 = slot ^ ((r0 >> 1) & 3);
  int gc1 = slot ^ ((r1 >> 1) & 3);
  const unsigned short* gA0 = xb + (size_t)s_tok[r0] * CD + gc0 * 8;
  const unsigned short* gA1 = xb + (size_t)s_tok[r1] * CD + gc1 * 8;
  const unsigned short* gB0 = wfcp + ((size_t)e * HD + n0 + r0) * CD + gc0 * 8;
  const unsigned short* gB1 = wfcp + ((size_t)e * HD + n0 + r1) * CD + gc1 * 8;
  unsigned short* lA0 = &lsA[(size_t)t * 8];
  unsigned short* lA1 = &lsA[(size_t)(256 + t) * 8];
  unsigned short* lB0 = &lsB[(size_t)t * 8];
  unsigned short* lB1 = &lsB[(size_t)(256 + t) * 8];

  int lane = t & 63, wv = t >> 6;
  int wm = (wv & 1) * 64, wn = (wv >> 1) * 64;
  int ml = lane & 15, kq = lane >> 4;

  f32x4_t acc[4][4];
  #pragma unroll
  for (int i = 0; i < 4; ++i)
    #pragma unroll
    for (int j = 0; j < 4; ++j) acc[i][j] = (f32x4_t){0.f, 0.f, 0.f, 0.f};

  for (int k0 = 0; k0 < CD; k0 += 32) {
    __syncthreads();
    gl2lds16(gA0 + k0, lA0);
    gl2lds16(gA1 + k0, lA1);
    gl2lds16(gB0 + k0, lB0);
    gl2lds16(gB1 + k0, lB1);
    __syncthreads();
    short8_t af[4], bfr[4];
    #pragma unroll
    for (int i = 0; i < 4; ++i) {
      int ar = wm + i * 16 + ml;
      af[i]  = *(const short8_t*)&lsA[swz(ar, kq) * 8];
      int br = wn + i * 16 + ml;
      bfr[i] = *(const short8_t*)&lsB[swz(br, kq) * 8];
    }
    #pragma unroll
    for (int i = 0; i < 4; ++i)
      #pragma unroll
      for (int j = 0; j < 4; ++j)
        acc[i][j] = __builtin_amdgcn_mfma_f32_16x16x32_bf16(
            FragArg{af[i]}, FragArg{bfr[j]}, acc[i][j], 0, 0, 0);
  }

  #pragma unroll
  for (int i = 0; i < 4; ++i) {
    int rb = wm + i * 16 + kq * 4;
    #pragma unroll
    for (int r = 0; r < 4; ++r) {
      int row = rb + r;
      if (m0 + row < cnt) {
        float v = s_v[row];
        size_t ro = (size_t)(base + m0 + row) * HD + n0;
        #pragma unroll
        for (int j = 0; j < 4; ++j) {
          float z = acc[i][j][r];
          float val = v * (z / (1.0f + __expf(-z)));   // gate_w * silu(z)
          hbuf[ro + wn + j * 16 + ml] = f2b(val);
        }
      }
    }
  }
}

// ------------------- GEMM2: o_slot = h_rows @ WprojT -----------------------
__global__ __launch_bounds__(256) void gemm2_kernel(
    const unsigned short* __restrict__ hbuf, const unsigned short* __restrict__ wpjp,
    const int* __restrict__ g_counts, const int* __restrict__ g_base,
    unsigned short* __restrict__ oslot)
{
  int e = blockIdx.z, mt = blockIdx.y, nt = blockIdx.x;
  int cnt = g_counts[e];
  int m0 = mt * 128;
  if (m0 >= cnt) return;
  int base = g_base[e];
  int n0 = nt * 128;

  __shared__ __align__(16) unsigned short lsA[128 * 32];
  __shared__ __align__(16) unsigned short lsB[128 * 32];

  int t = threadIdx.x;
  int slot = t & 3;
  int r0 = t >> 2, r1 = r0 + 64;
  int gc0 = slot ^ ((r0 >> 1) & 3);
  int gc1 = slot ^ ((r1 >> 1) & 3);
  // Padded rows may over-read past hbuf into the oslot region (still inside
  // d_ws) — their stores are guarded below.
  const unsigned short* gA0 = hbuf + (size_t)(base + m0 + r0) * HD + gc0 * 8;
  const unsigned short* gA1 = hbuf + (size_t)(base + m0 + r1) * HD + gc1 * 8;
  const unsigned short* gB0 = wpjp + ((size_t)e * CD + n0 + r0) * HD + gc0 * 8;
  const unsigned short* gB1 = wpjp + ((size_t)e * CD + n0 + r1) * HD + gc1 * 8;
  unsigned short* lA0 = &lsA[(size_t)t * 8];
  unsigned short* lA1 = &lsA[(size_t)(256 + t) * 8];
  unsigned short* lB0 = &lsB[(size_t)t * 8];
  unsigned short* lB1 = &lsB[(size_t)(256 + t) * 8];

  int lane = t & 63, wv = t >> 6;
  int wm = (wv & 1) * 64, wn = (wv >> 1) * 64;
  int ml = lane & 15, kq = lane >> 4;

  f32x4_t acc[4][4];
  #pragma unroll
  for (int i = 0; i < 4; ++i)
    #pragma unroll
    for (int j = 0; j < 4; ++j) acc[i][j] = (f32x4_t){0.f, 0.f, 0.f, 0.f};

  for (int k0 = 0; k0 < HD; k0 += 32) {
    __syncthreads();
    gl2lds16(gA0 + k0, lA0);
    gl2lds16(gA1 + k0, lA1);
    gl2lds16(gB0 + k0, lB0);
    gl2lds16(gB1 + k0, lB1);
    __syncthreads();
    short8_t af[4], bfr[4];
    #pragma unroll
    for (int i = 0; i < 4; ++i) {
      int ar = wm + i * 16 + ml;
      af[i]  = *(const short8_t*)&lsA[swz(ar, kq) * 8];
      int br = wn + i * 16 + ml;
      bfr[i] = *(const short8_t*)&lsB[swz(br, kq) * 8];
    }
    #pragma unroll
    for (int i = 0; i < 4; ++i)
      #pragma unroll
      for (int j = 0; j < 4; ++j)
        acc[i][j] = __builtin_amdgcn_mfma_f32_16x16x32_bf16(
            FragArg{af[i]}, FragArg{bfr[j]}, acc[i][j], 0, 0, 0);
  }

  #pragma unroll
  for (int i = 0; i < 4; ++i) {
    int rb = wm + i * 16 + kq * 4;
    #pragma unroll
    for (int r = 0; r < 4; ++r) {
      int row = rb + r;
      if (m0 + row < cnt) {
        size_t ro = (size_t)(base + m0 + row) * CD + n0;
        #pragma unroll
        for (int j = 0; j < 4; ++j)
          oslot[ro + wn + j * 16 + ml] = f2b(acc[i][j][r]);
      }
    }
  }
}

// ----------- combine: out[t] = fp32(oslot[s0]) + fp32(oslot[s1]) -----------
__global__ __launch_bounds__(256) void combine_kernel(
    const unsigned short* __restrict__ oslot, const int* __restrict__ slot_of,
    float* __restrict__ out)
{
  int gid = blockIdx.x * 256 + threadIdx.x;
  int tk = gid >> 7;               // 128 chunks of 8 per token
  int ch = (gid & 127) * 8;
  int s0 = slot_of[tk * 2], s1 = slot_of[tk * 2 + 1];
  short8_t a = *(const short8_t*)(oslot + (size_t)s0 * CD + ch);
  short8_t b = *(const short8_t*)(oslot + (size_t)s1 * CD + ch);
  float* op = out + (size_t)tk * CD + ch;
  float4 o0, o1;
  o0.x = b2f((unsigned short)a[0]) + b2f((unsigned short)b[0]);
  o0.y = b2f((unsigned short)a[1]) + b2f((unsigned short)b[1]);
  o0.z = b2f((unsigned short)a[2]) + b2f((unsigned short)b[2]);
  o0.w = b2f((unsigned short)a[3]) + b2f((unsigned short)b[3]);
  o1.x = b2f((unsigned short)a[4]) + b2f((unsigned short)b[4]);
  o1.y = b2f((unsigned short)a[5]) + b2f((unsigned short)b[5]);
  o1.z = b2f((unsigned short)a[6]) + b2f((unsigned short)b[6]);
  o1.w = b2f((unsigned short)a[7]) + b2f((unsigned short)b[7]);
  *(float4*)op = o0;
  *(float4*)(op + 4) = o1;
}

// ---------------------------------------------------------------------------
extern "C" void kernel_launch(void* const* d_in, const int* in_sizes, int n_in,
                              void* d_out, int out_size, void* d_ws, size_t ws_size,
                              hipStream_t stream)
{
  const float* x   = (const float*)d_in[0];
  const float* wg  = (const float*)d_in[1];
  const float* wfc = (const float*)d_in[2];
  const float* wpj = (const float*)d_in[3];
  float* out = (float*)d_out;

  // workspace carve-up (~185 MB). hbuf precedes oslot so padded-tile A
  // over-reads in gemm2 stay inside d_ws.
  char* w = (char*)d_ws;
  unsigned short* wfcp  = (unsigned short*)w; w += (size_t)NE * HD * CD * 2;  // 33.5 MB
  unsigned short* wpjp  = (unsigned short*)w; w += (size_t)NE * CD * HD * 2;  // 33.5 MB
  unsigned short* xb    = (unsigned short*)w; w += (size_t)NTOK * CD * 2;     // 16.8 MB
  unsigned short* hbuf  = (unsigned short*)w; w += (size_t)NSLOT * HD * 2;    // 67.1 MB
  unsigned short* oslot = (unsigned short*)w; w += (size_t)NSLOT * CD * 2;    // 33.5 MB
  int*   tok_e      = (int*)w;   w += NSLOT * 4;
  float* tok_v      = (float*)w; w += NSLOT * 4;
  int*   slot_of    = (int*)w;   w += NSLOT * 4;
  int*   bucket_tok = (int*)w;   w += NSLOT * 4;
  float* bucket_v   = (float*)w; w += NSLOT * 4;
  int*   g_counts   = (int*)w;   w += 256;
  int*   g_base     = (int*)w;   w += 256;

  // w_fc (C,H,E) -> wfcp (E,H,C);  w_proj (H,C,E) -> wpjp (E,C,H)
  pack_kernel<<<dim3(HD / 32, CD / 32), 256, 0, stream>>>(wfc, wfcp, CD, HD);
  pack_kernel<<<dim3(CD / 32, HD / 32), 256, 0, stream>>>(wpj, wpjp, HD, CD);
  cvt_x_kernel<<<(NTOK * CD / 8) / 256, 256, 0, stream>>>(x, xb);
  gate_kernel<<<NTOK / 4, 256, 0, stream>>>(x, wg, tok_e, tok_v);
  router_kernel<<<1, 256, 0, stream>>>(tok_e, tok_v, g_counts, g_base,
                                       bucket_tok, bucket_v, slot_of);
  gemm1_kernel<<<dim3(HD / 128, MTILES, NE), 256, 0, stream>>>(
      xb, wfcp, g_counts, g_base, bucket_tok, bucket_v, hbuf);
  gemm2_kernel<<<dim3(CD / 128, MTILES, NE), 256, 0, stream>>>(
      hbuf, wpjp, g_counts, g_base, oslot);
  combine_kernel<<<(NTOK * CD / 8) / 256, 256, 0, stream>>>(oslot, slot_of, out);
}

// Round 3
// 478.354 us; speedup vs baseline: 1.0414x; 1.0414x over previous
//
#include <hip/hip_runtime.h>
#include <hip/hip_bf16.h>

// ---------------------------------------------------------------------------
// MoE (top-2 of 8 experts), B=4 T=2048 C=1024 H=2048 E=8. FP32 in/out;
// internal GEMMs in bf16 MFMA. Round 3: XCD-locality swizzle on both GEMMs
// (n-tiles sharing an A-panel stay on one XCD's L2), cvt fused into gate,
// atomic-free router, packs fused into one dispatch. 6 kernels total.
// ---------------------------------------------------------------------------

#define NTOK 8192
#define CD   1024
#define HD   2048
#define NE   8
#define NSLOT 16384   // NTOK * top_k
#define MTILES 32     // supports up to 4096 tokens per expert (mean 2048)

typedef short  short4_t  __attribute__((ext_vector_type(4)));
typedef short  short8_t  __attribute__((ext_vector_type(8)));
typedef __bf16 bf16x8_t  __attribute__((ext_vector_type(8)));
typedef float  f32x4_t   __attribute__((ext_vector_type(4)));

// MFMA builtin arg-type shim: satisfies either V8s or V8bf16 signatures.
struct FragArg {
  short8_t v;
  __device__ operator short8_t() const { return v; }
  __device__ operator bf16x8_t() const { return __builtin_bit_cast(bf16x8_t, v); }
};

static __device__ __forceinline__ float b2f(unsigned short u) {
  union { float f; unsigned int i; } w; w.i = ((unsigned int)u) << 16; return w.f;
}
static __device__ __forceinline__ unsigned short f2b(float f) {
  unsigned int u = __float_as_uint(f);
  u += 0x7fffu + ((u >> 16) & 1u);           // round-to-nearest-even
  return (unsigned short)(u >> 16);
}
static __device__ __forceinline__ void gl2lds16(const void* g, void* l) {
  __builtin_amdgcn_global_load_lds((__attribute__((address_space(1))) void*)g,
                                   (__attribute__((address_space(3))) void*)l,
                                   16, 0, 0);
}
// XOR swizzle: 16B-chunk slot for (row, k-chunk); fragment reads 2-way (free).
static __device__ __forceinline__ int swz(int row, int kc) {
  return row * 4 + (kc ^ ((row >> 1) & 3));
}

// ------------------- gating (fp32) + x -> bf16 conversion ------------------
__global__ __launch_bounds__(256) void gate_kernel(
    const float* __restrict__ x, const float* __restrict__ wg,
    unsigned short* __restrict__ xb,
    int* __restrict__ tok_e, float* __restrict__ tok_v)
{
  int wv = threadIdx.x >> 6, lane = threadIdx.x & 63;
  int tk = blockIdx.x * 4 + wv;               // one wave per token
  const float* xr = x + (size_t)tk * CD;
  unsigned short* xbr = xb + (size_t)tk * CD;
  float acc[NE] = {0, 0, 0, 0, 0, 0, 0, 0};
  #pragma unroll
  for (int jj = 0; jj < 4; ++jj) {
    int c0 = (lane + 64 * jj) * 4;            // 4 channels per float4
    float4 xv = *(const float4*)(xr + c0);
    short4_t ob;                               // fused fp32->bf16 of x
    ob[0] = (short)f2b(xv.x); ob[1] = (short)f2b(xv.y);
    ob[2] = (short)f2b(xv.z); ob[3] = (short)f2b(xv.w);
    *(short4_t*)(xbr + c0) = ob;
    #pragma unroll
    for (int j = 0; j < 4; ++j) {
      float xf = (j == 0) ? xv.x : (j == 1) ? xv.y : (j == 2) ? xv.z : xv.w;
      const float* wr = wg + (size_t)(c0 + j) * NE;
      float4 w0 = *(const float4*)wr;
      float4 w1 = *(const float4*)(wr + 4);
      acc[0] += xf * w0.x; acc[1] += xf * w0.y;
      acc[2] += xf * w0.z; acc[3] += xf * w0.w;
      acc[4] += xf * w1.x; acc[5] += xf * w1.y;
      acc[6] += xf * w1.z; acc[7] += xf * w1.w;
    }
  }
  #pragma unroll
  for (int off = 32; off >= 1; off >>= 1)
    #pragma unroll
    for (int e = 0; e < NE; ++e) acc[e] += __shfl_down(acc[e], off, 64);
  if (lane == 0) {
    float v1 = -3.0e38f, v2 = -3.0e38f; int i1 = 0, i2 = 1;
    #pragma unroll
    for (int e = 0; e < NE; ++e) {            // strict '>' => ties keep lower idx
      float g = acc[e];
      if (g > v1) { v2 = v1; i2 = i1; v1 = g; i1 = e; }
      else if (g > v2) { v2 = g; i2 = e; }
    }
    tok_e[tk * 2] = i1; tok_e[tk * 2 + 1] = i2;
    tok_v[tk * 2] = v1; tok_v[tk * 2 + 1] = v2;
  }
}

// ------------------- router (1 block, atomic-free scan) --------------------
__global__ __launch_bounds__(256) void router_kernel(
    const int* __restrict__ tok_e, const float* __restrict__ tok_v,
    int* __restrict__ g_counts, int* __restrict__ g_base,
    int* __restrict__ bucket_tok, float* __restrict__ bucket_v,
    int* __restrict__ slot_of)
{
  __shared__ int cnts[NE][256];   // per-thread per-expert counts -> excl offsets
  __shared__ int bas[NE], tot[NE];
  int t = threadIdx.x;
  int local[NE] = {0, 0, 0, 0, 0, 0, 0, 0};
  for (int i = 0; i < 64; ++i) local[tok_e[t * 64 + i]]++;
  #pragma unroll
  for (int e = 0; e < NE; ++e) cnts[e][t] = local[e];
  __syncthreads();
  int lane = t & 63, wv = t >> 6;
  for (int e = wv; e < NE; e += 4) {          // wave wv scans experts wv, wv+4
    int carry = 0;
    #pragma unroll
    for (int c = 0; c < 4; ++c) {
      int v = cnts[e][c * 64 + lane];
      int incl = v;
      #pragma unroll
      for (int off = 1; off < 64; off <<= 1) {
        int n = __shfl_up(incl, off, 64);
        if (lane >= off) incl += n;
      }
      cnts[e][c * 64 + lane] = incl - v + carry;   // exclusive offset
      carry += __shfl(incl, 63, 64);
    }
    if (lane == 0) tot[e] = carry;
  }
  __syncthreads();
  if (t == 0) { int o = 0; for (int e = 0; e < NE; ++e) { bas[e] = o; o += tot[e]; } }
  __syncthreads();
  if (t < NE) { g_counts[t] = tot[t]; g_base[t] = bas[t]; }
  for (int i = 0; i < 64; ++i) {
    int s = t * 64 + i;
    int e = tok_e[s];
    int sl = bas[e] + cnts[e][t];             // per-thread-owned cursor in LDS
    cnts[e][t]++;
    bucket_tok[sl] = s >> 1;
    bucket_v[sl]   = tok_v[s];
    slot_of[s]     = sl;
  }
}

// ---- fused weight pack: fp32 (D0,D1,8) -> bf16 (8,D1,D0), both tensors ----
__global__ __launch_bounds__(256) void pack_kernel(
    const float* __restrict__ wfc, const float* __restrict__ wpj,
    unsigned short* __restrict__ wfcp, unsigned short* __restrict__ wpjp)
{
  __shared__ __align__(16) unsigned short lds[NE * 32 * 40];
  const float* in; unsigned short* out; int D0, D1, b0, b1;
  if (blockIdx.z == 0) { in = wfc; out = wfcp; D0 = CD; D1 = HD;
                         b1 = blockIdx.x * 32; b0 = blockIdx.y * 32; }
  else                 { in = wpj; out = wpjp; D0 = HD; D1 = CD;
                         b1 = blockIdx.y * 32; b0 = blockIdx.x * 32; }
  int t = threadIdx.x;
  int d1i = t & 31, d0q = t >> 5;
  #pragma unroll
  for (int r = 0; r < 4; ++r) {
    int d0i = d0q * 4 + r;
    const float* src = in + ((size_t)(b0 + d0i) * D1 + (b1 + d1i)) * NE;
    float4 v0 = *(const float4*)src;
    float4 v1 = *(const float4*)(src + 4);
    unsigned short* dst0 = &lds[d1i * 40 + d0i];
    dst0[0 * 32 * 40] = f2b(v0.x);
    dst0[1 * 32 * 40] = f2b(v0.y);
    dst0[2 * 32 * 40] = f2b(v0.z);
    dst0[3 * 32 * 40] = f2b(v0.w);
    dst0[4 * 32 * 40] = f2b(v1.x);
    dst0[5 * 32 * 40] = f2b(v1.y);
    dst0[6 * 32 * 40] = f2b(v1.z);
    dst0[7 * 32 * 40] = f2b(v1.w);
  }
  __syncthreads();
  int dchunk = t & 3, d1w = (t >> 2) & 31, ehalf = t >> 7;
  #pragma unroll
  for (int p = 0; p < 4; ++p) {
    int e = ehalf + 2 * p;
    short8_t v = *(const short8_t*)&lds[e * 32 * 40 + d1w * 40 + dchunk * 8];
    *(short8_t*)(out + ((size_t)e * D1 + (b1 + d1w)) * D0 + b0 + dchunk * 8) = v;
  }
}

// ------------------- GEMM1: h = v * silu(x_rows @ WfcT) --------------------
// 1-D grid, XCD-swizzled: xcd = id&7; nt iterates fastest within one XCD so
// all 16 n-tiles sharing an A-panel hit the same per-XCD L2.
__global__ __launch_bounds__(256) void gemm1_kernel(
    const unsigned short* __restrict__ xb, const unsigned short* __restrict__ wfcp,
    const int* __restrict__ g_counts, const int* __restrict__ g_base,
    const int* __restrict__ bucket_tok, const float* __restrict__ bucket_v,
    unsigned short* __restrict__ hbuf)
{
  int id = blockIdx.x;
  int xcd = id & 7;
  int r = id >> 3;
  int nt = r & 15;                 // HD/128 = 16 n-tiles, fastest per XCD
  int emt = (r >> 4) * 8 + xcd;    // (e,mt) group pinned to this XCD
  int e = emt >> 5, mt = emt & 31;

  int cnt = g_counts[e];
  int m0 = mt * 128;
  if (m0 >= cnt) return;
  int base = g_base[e];
  int n0 = nt * 128;

  __shared__ __align__(16) unsigned short lsA[128 * 32];
  __shared__ __align__(16) unsigned short lsB[128 * 32];
  __shared__ int   s_tok[128];
  __shared__ float s_v[128];

  int t = threadIdx.x;
  if (t < 128) {
    int ok = (m0 + t) < cnt;
    s_tok[t] = ok ? bucket_tok[base + m0 + t] : 0;
    s_v[t]   = ok ? bucket_v[base + m0 + t] : 0.0f;
  }
  __syncthreads();

  int slot = t & 3;
  int r0 = t >> 2, r1 = r0 + 64;              // each thread stages 2 rows x 16B
  int gc0 = slot ^ ((r0 >> 1) & 3);
  int gc1 = slot ^ ((r1 >> 1) & 3);
  const unsigned short* gA0 = xb + (size_t)s_tok[r0] * CD + gc0 * 8;
  const unsigned short* gA1 = xb + (size_t)s_tok[r1] * CD + gc1 * 8;
  const unsigned short* gB0 = wfcp + ((size_t)e * HD + n0 + r0) * CD + gc0 * 8;
  const unsigned short* gB1 = wfcp + ((size_t)e * HD + n0 + r1) * CD + gc1 * 8;
  unsigned short* lA0 = &lsA[(size_t)t * 8];
  unsigned short* lA1 = &lsA[(size_t)(256 + t) * 8];
  unsigned short* lB0 = &lsB[(size_t)t * 8];
  unsigned short* lB1 = &lsB[(size_t)(256 + t) * 8];

  int lane = t & 63, wv = t >> 6;
  int wm = (wv & 1) * 64, wn = (wv >> 1) * 64;
  int ml = lane & 15, kq = lane >> 4;

  f32x4_t acc[4][4];
  #pragma unroll
  for (int i = 0; i < 4; ++i)
    #pragma unroll
    for (int j = 0; j < 4; ++j) acc[i][j] = (f32x4_t){0.f, 0.f, 0.f, 0.f};

  for (int k0 = 0; k0 < CD; k0 += 32) {
    __syncthreads();
    gl2lds16(gA0 + k0, lA0);
    gl2lds16(gA1 + k0, lA1);
    gl2lds16(gB0 + k0, lB0);
    gl2lds16(gB1 + k0, lB1);
    __syncthreads();
    short8_t af[4], bfr[4];
    #pragma unroll
    for (int i = 0; i < 4; ++i) {
      af[i]  = *(const short8_t*)&lsA[swz(wm + i * 16 + ml, kq) * 8];
      bfr[i] = *(const short8_t*)&lsB[swz(wn + i * 16 + ml, kq) * 8];
    }
    #pragma unroll
    for (int i = 0; i < 4; ++i)
      #pragma unroll
      for (int j = 0; j < 4; ++j)
        acc[i][j] = __builtin_amdgcn_mfma_f32_16x16x32_bf16(
            FragArg{af[i]}, FragArg{bfr[j]}, acc[i][j], 0, 0, 0);
  }

  #pragma unroll
  for (int i = 0; i < 4; ++i) {
    int rb = wm + i * 16 + kq * 4;
    #pragma unroll
    for (int r2 = 0; r2 < 4; ++r2) {
      int row = rb + r2;
      if (m0 + row < cnt) {
        float v = s_v[row];
        size_t ro = (size_t)(base + m0 + row) * HD + n0;
        #pragma unroll
        for (int j = 0; j < 4; ++j) {
          float z = acc[i][j][r2];
          float val = v * (z / (1.0f + __expf(-z)));   // gate_w * silu(z)
          hbuf[ro + wn + j * 16 + ml] = f2b(val);
        }
      }
    }
  }
}

// ------------------- GEMM2: o_slot = h_rows @ WprojT -----------------------
__global__ __launch_bounds__(256) void gemm2_kernel(
    const unsigned short* __restrict__ hbuf, const unsigned short* __restrict__ wpjp,
    const int* __restrict__ g_counts, const int* __restrict__ g_base,
    unsigned short* __restrict__ oslot)
{
  int id = blockIdx.x;
  int xcd = id & 7;
  int r = id >> 3;
  int nt = r & 7;                  // CD/128 = 8 n-tiles, fastest per XCD
  int emt = (r >> 3) * 8 + xcd;
  int e = emt >> 5, mt = emt & 31;

  int cnt = g_counts[e];
  int m0 = mt * 128;
  if (m0 >= cnt) return;
  int base = g_base[e];
  int n0 = nt * 128;

  __shared__ __align__(16) unsigned short lsA[128 * 32];
  __shared__ __align__(16) unsigned short lsB[128 * 32];

  int t = threadIdx.x;
  int slot = t & 3;
  int r0 = t >> 2, r1 = r0 + 64;
  int gc0 = slot ^ ((r0 >> 1) & 3);
  int gc1 = slot ^ ((r1 >> 1) & 3);
  // Padded rows may over-read past hbuf into the oslot region (inside d_ws);
  // their stores are guarded below.
  const unsigned short* gA0 = hbuf + (size_t)(base + m0 + r0) * HD + gc0 * 8;
  const unsigned short* gA1 = hbuf + (size_t)(base + m0 + r1) * HD + gc1 * 8;
  const unsigned short* gB0 = wpjp + ((size_t)e * CD + n0 + r0) * HD + gc0 * 8;
  const unsigned short* gB1 = wpjp + ((size_t)e * CD + n0 + r1) * HD + gc1 * 8;
  unsigned short* lA0 = &lsA[(size_t)t * 8];
  unsigned short* lA1 = &lsA[(size_t)(256 + t) * 8];
  unsigned short* lB0 = &lsB[(size_t)t * 8];
  unsigned short* lB1 = &lsB[(size_t)(256 + t) * 8];

  int lane = t & 63, wv = t >> 6;
  int wm = (wv & 1) * 64, wn = (wv >> 1) * 64;
  int ml = lane & 15, kq = lane >> 4;

  f32x4_t acc[4][4];
  #pragma unroll
  for (int i = 0; i < 4; ++i)
    #pragma unroll
    for (int j = 0; j < 4; ++j) acc[i][j] = (f32x4_t){0.f, 0.f, 0.f, 0.f};

  for (int k0 = 0; k0 < HD; k0 += 32) {
    __syncthreads();
    gl2lds16(gA0 + k0, lA0);
    gl2lds16(gA1 + k0, lA1);
    gl2lds16(gB0 + k0, lB0);
    gl2lds16(gB1 + k0, lB1);
    __syncthreads();
    short8_t af[4], bfr[4];
    #pragma unroll
    for (int i = 0; i < 4; ++i) {
      af[i]  = *(const short8_t*)&lsA[swz(wm + i * 16 + ml, kq) * 8];
      bfr[i] = *(const short8_t*)&lsB[swz(wn + i * 16 + ml, kq) * 8];
    }
    #pragma unroll
    for (int i = 0; i < 4; ++i)
      #pragma unroll
      for (int j = 0; j < 4; ++j)
        acc[i][j] = __builtin_amdgcn_mfma_f32_16x16x32_bf16(
            FragArg{af[i]}, FragArg{bfr[j]}, acc[i][j], 0, 0, 0);
  }

  #pragma unroll
  for (int i = 0; i < 4; ++i) {
    int rb = wm + i * 16 + kq * 4;
    #pragma unroll
    for (int r2 = 0; r2 < 4; ++r2) {
      int row = rb + r2;
      if (m0 + row < cnt) {
        size_t ro = (size_t)(base + m0 + row) * CD + n0;
        #pragma unroll
        for (int j = 0; j < 4; ++j)
          oslot[ro + wn + j * 16 + ml] = f2b(acc[i][j][r2]);
      }
    }
  }
}

// ----------- combine: out[t] = fp32(oslot[s0]) + fp32(oslot[s1]) -----------
__global__ __launch_bounds__(256) void combine_kernel(
    const unsigned short* __restrict__ oslot, const int* __restrict__ slot_of,
    float* __restrict__ out)
{
  int gid = blockIdx.x * 256 + threadIdx.x;
  int tk = gid >> 7;               // 128 chunks of 8 per token
  int ch = (gid & 127) * 8;
  int s0 = slot_of[tk * 2], s1 = slot_of[tk * 2 + 1];
  short8_t a = *(const short8_t*)(oslot + (size_t)s0 * CD + ch);
  short8_t b = *(const short8_t*)(oslot + (size_t)s1 * CD + ch);
  float* op = out + (size_t)tk * CD + ch;
  float4 o0, o1;
  o0.x = b2f((unsigned short)a[0]) + b2f((unsigned short)b[0]);
  o0.y = b2f((unsigned short)a[1]) + b2f((unsigned short)b[1]);
  o0.z = b2f((unsigned short)a[2]) + b2f((unsigned short)b[2]);
  o0.w = b2f((unsigned short)a[3]) + b2f((unsigned short)b[3]);
  o1.x = b2f((unsigned short)a[4]) + b2f((unsigned short)b[4]);
  o1.y = b2f((unsigned short)a[5]) + b2f((unsigned short)b[5]);
  o1.z = b2f((unsigned short)a[6]) + b2f((unsigned short)b[6]);
  o1.w = b2f((unsigned short)a[7]) + b2f((unsigned short)b[7]);
  *(float4*)op = o0;
  *(float4*)(op + 4) = o1;
}

// ---------------------------------------------------------------------------
extern "C" void kernel_launch(void* const* d_in, const int* in_sizes, int n_in,
                              void* d_out, int out_size, void* d_ws, size_t ws_size,
                              hipStream_t stream)
{
  const float* x   = (const float*)d_in[0];
  const float* wg  = (const float*)d_in[1];
  const float* wfc = (const float*)d_in[2];
  const float* wpj = (const float*)d_in[3];
  float* out = (float*)d_out;

  // workspace carve-up (~185 MB). hbuf precedes oslot so padded-tile A
  // over-reads in gemm2 stay inside d_ws.
  char* w = (char*)d_ws;
  unsigned short* wfcp  = (unsigned short*)w; w += (size_t)NE * HD * CD * 2;  // 33.5 MB
  unsigned short* wpjp  = (unsigned short*)w; w += (size_t)NE * CD * HD * 2;  // 33.5 MB
  unsigned short* xb    = (unsigned short*)w; w += (size_t)NTOK * CD * 2;     // 16.8 MB
  unsigned short* hbuf  = (unsigned short*)w; w += (size_t)NSLOT * HD * 2;    // 67.1 MB
  unsigned short* oslot = (unsigned short*)w; w += (size_t)NSLOT * CD * 2;    // 33.5 MB
  int*   tok_e      = (int*)w;   w += NSLOT * 4;
  float* tok_v      = (float*)w; w += NSLOT * 4;
  int*   slot_of    = (int*)w;   w += NSLOT * 4;
  int*   bucket_tok = (int*)w;   w += NSLOT * 4;
  float* bucket_v   = (float*)w; w += NSLOT * 4;
  int*   g_counts   = (int*)w;   w += 256;
  int*   g_base     = (int*)w;   w += 256;

  gate_kernel<<<NTOK / 4, 256, 0, stream>>>(x, wg, xb, tok_e, tok_v);
  router_kernel<<<1, 256, 0, stream>>>(tok_e, tok_v, g_counts, g_base,
                                       bucket_tok, bucket_v, slot_of);
  pack_kernel<<<dim3(HD / 32, CD / 32, 2), 256, 0, stream>>>(wfc, wpj, wfcp, wpjp);
  gemm1_kernel<<<(HD / 128) * MTILES * NE, 256, 0, stream>>>(
      xb, wfcp, g_counts, g_base, bucket_tok, bucket_v, hbuf);
  gemm2_kernel<<<(CD / 128) * MTILES * NE, 256, 0, stream>>>(
      hbuf, wpjp, g_counts, g_base, oslot);
  combine_kernel<<<(NTOK * CD / 8) / 256, 256, 0, stream>>>(oslot, slot_of, out);
}

// Round 4
// 466.440 us; speedup vs baseline: 1.0680x; 1.0255x over previous
//
#include <hip/hip_runtime.h>
#include <hip/hip_bf16.h>

// ---------------------------------------------------------------------------
// MoE (top-2 of 8 experts), B=4 T=2048 C=1024 H=2048 E=8. FP32 in/out;
// internal GEMMs in bf16 MFMA. Round 4: gate+pack fused into one dispatch
// (independent work, one launch), router -> 64-block wave-aggregated-atomic
// scatter, memset node for counters, MTILES 32->20. GEMM structure unchanged
// (m97 ladder + XCD-locality swizzle).
// ---------------------------------------------------------------------------

#define NTOK 8192
#define CD   1024
#define HD   2048
#define NE   8
#define NSLOT 16384   // NTOK * top_k
#define MTILES 20     // supports up to 2560 tokens per expert (mean 2048, 12 sigma)

typedef short  short4_t  __attribute__((ext_vector_type(4)));
typedef short  short8_t  __attribute__((ext_vector_type(8)));
typedef __bf16 bf16x8_t  __attribute__((ext_vector_type(8)));
typedef float  f32x4_t   __attribute__((ext_vector_type(4)));

// MFMA builtin arg-type shim: satisfies either V8s or V8bf16 signatures.
struct FragArg {
  short8_t v;
  __device__ operator short8_t() const { return v; }
  __device__ operator bf16x8_t() const { return __builtin_bit_cast(bf16x8_t, v); }
};

static __device__ __forceinline__ float b2f(unsigned short u) {
  union { float f; unsigned int i; } w; w.i = ((unsigned int)u) << 16; return w.f;
}
static __device__ __forceinline__ unsigned short f2b(float f) {
  unsigned int u = __float_as_uint(f);
  u += 0x7fffu + ((u >> 16) & 1u);           // round-to-nearest-even
  return (unsigned short)(u >> 16);
}
static __device__ __forceinline__ void gl2lds16(const void* g, void* l) {
  __builtin_amdgcn_global_load_lds((__attribute__((address_space(1))) void*)g,
                                   (__attribute__((address_space(3))) void*)l,
                                   16, 0, 0);
}
// XOR swizzle: 16B-chunk slot for (row, k-chunk); fragment reads 2-way (free).
static __device__ __forceinline__ int swz(int row, int kc) {
  return row * 4 + (kc ^ ((row >> 1) & 3));
}

// ---- fused prep: blocks [0,2048) = gate(+x->bf16, +histogram);
//      blocks [2048,6144) = weight pack fp32 (D0,D1,8) -> bf16 (8,D1,D0) ----
#define GATE_BLOCKS (NTOK / 4)
__global__ __launch_bounds__(256) void prep_kernel(
    const float* __restrict__ x, const float* __restrict__ wg,
    const float* __restrict__ wfc, const float* __restrict__ wpj,
    unsigned short* __restrict__ xb,
    unsigned short* __restrict__ wfcp, unsigned short* __restrict__ wpjp,
    int* __restrict__ tok_e, float* __restrict__ tok_v,
    int* __restrict__ g_counts)
{
  __shared__ __align__(16) unsigned short lds[NE * 32 * 40];  // pack role
  __shared__ int hist[NE];                                    // gate role
  int t = threadIdx.x;

  if (blockIdx.x < GATE_BLOCKS) {
    // ---------------- gate role: one wave per token ----------------
    if (t < NE) hist[t] = 0;
    __syncthreads();
    int wv = t >> 6, lane = t & 63;
    int tk = blockIdx.x * 4 + wv;
    const float* xr = x + (size_t)tk * CD;
    unsigned short* xbr = xb + (size_t)tk * CD;
    float acc[NE] = {0, 0, 0, 0, 0, 0, 0, 0};
    #pragma unroll
    for (int jj = 0; jj < 4; ++jj) {
      int c0 = (lane + 64 * jj) * 4;
      float4 xv = *(const float4*)(xr + c0);
      short4_t ob;                             // fused fp32->bf16 of x
      ob[0] = (short)f2b(xv.x); ob[1] = (short)f2b(xv.y);
      ob[2] = (short)f2b(xv.z); ob[3] = (short)f2b(xv.w);
      *(short4_t*)(xbr + c0) = ob;
      #pragma unroll
      for (int j = 0; j < 4; ++j) {
        float xf = (j == 0) ? xv.x : (j == 1) ? xv.y : (j == 2) ? xv.z : xv.w;
        const float* wr = wg + (size_t)(c0 + j) * NE;
        float4 w0 = *(const float4*)wr;
        float4 w1 = *(const float4*)(wr + 4);
        acc[0] += xf * w0.x; acc[1] += xf * w0.y;
        acc[2] += xf * w0.z; acc[3] += xf * w0.w;
        acc[4] += xf * w1.x; acc[5] += xf * w1.y;
        acc[6] += xf * w1.z; acc[7] += xf * w1.w;
      }
    }
    #pragma unroll
    for (int off = 32; off >= 1; off >>= 1)
      #pragma unroll
      for (int e = 0; e < NE; ++e) acc[e] += __shfl_down(acc[e], off, 64);
    if (lane == 0) {
      float v1 = -3.0e38f, v2 = -3.0e38f; int i1 = 0, i2 = 1;
      #pragma unroll
      for (int e = 0; e < NE; ++e) {          // strict '>' => ties keep lower idx
        float g = acc[e];
        if (g > v1) { v2 = v1; i2 = i1; v1 = g; i1 = e; }
        else if (g > v2) { v2 = g; i2 = e; }
      }
      tok_e[tk * 2] = i1; tok_e[tk * 2 + 1] = i2;
      tok_v[tk * 2] = v1; tok_v[tk * 2 + 1] = v2;
      atomicAdd(&hist[i1], 1); atomicAdd(&hist[i2], 1);
    }
    __syncthreads();
    if (t < NE && hist[t] > 0) atomicAdd(&g_counts[t], hist[t]);
  } else {
    // ---------------- pack role ----------------
    int pid = blockIdx.x - GATE_BLOCKS;       // [0, 4096)
    int tensor = pid >> 11;                   // 2048 blocks per tensor
    int rem = pid & 2047;
    int bx = rem & 63, by = rem >> 6;         // 64 x 32 tile grid
    const float* in; unsigned short* out; int D0, D1, b0, b1;
    if (tensor == 0) { in = wfc; out = wfcp; D0 = CD; D1 = HD;
                       b1 = bx * 32; b0 = by * 32; }   // D1/32=64? no: bx covers D1 tiles
    else             { in = wpj; out = wpjp; D0 = HD; D1 = CD;
                       b1 = by * 32; b0 = bx * 32; }
    // tensor0: D1=HD has 64 tiles (bx), D0=CD has 32 (by).
    // tensor1: D0=HD has 64 tiles (bx), D1=CD has 32 (by).
    int d1i = t & 31, d0q = t >> 5;
    #pragma unroll
    for (int r = 0; r < 4; ++r) {
      int d0i = d0q * 4 + r;
      const float* src = in + ((size_t)(b0 + d0i) * D1 + (b1 + d1i)) * NE;
      float4 v0 = *(const float4*)src;
      float4 v1 = *(const float4*)(src + 4);
      unsigned short* dst0 = &lds[d1i * 40 + d0i];
      dst0[0 * 32 * 40] = f2b(v0.x);
      dst0[1 * 32 * 40] = f2b(v0.y);
      dst0[2 * 32 * 40] = f2b(v0.z);
      dst0[3 * 32 * 40] = f2b(v0.w);
      dst0[4 * 32 * 40] = f2b(v1.x);
      dst0[5 * 32 * 40] = f2b(v1.y);
      dst0[6 * 32 * 40] = f2b(v1.z);
      dst0[7 * 32 * 40] = f2b(v1.w);
    }
    __syncthreads();
    int dchunk = t & 3, d1w = (t >> 2) & 31, ehalf = t >> 7;
    #pragma unroll
    for (int p = 0; p < 4; ++p) {
      int e = ehalf + 2 * p;
      short8_t v = *(const short8_t*)&lds[e * 32 * 40 + d1w * 40 + dchunk * 8];
      *(short8_t*)(out + ((size_t)e * D1 + (b1 + d1w)) * D0 + b0 + dchunk * 8) = v;
    }
  }
}

// ------ scatter: 64 blocks, wave-aggregated atomics on g_cursor ------------
__global__ __launch_bounds__(256) void scatter_kernel(
    const int* __restrict__ tok_e, const float* __restrict__ tok_v,
    const int* __restrict__ g_counts, int* __restrict__ g_cursor,
    int* __restrict__ g_base,
    int* __restrict__ bucket_tok, float* __restrict__ bucket_v,
    int* __restrict__ slot_of)
{
  int gid = blockIdx.x * 256 + threadIdx.x;   // 16384 threads, 1 slot each
  int lane = threadIdx.x & 63;
  int base[NE];
  { int o = 0;
    #pragma unroll
    for (int e = 0; e < NE; ++e) { base[e] = o; o += g_counts[e]; } }
  int e = tok_e[gid];
  unsigned long long lanebit = 1ull << lane;
  int pos = 0;
  #pragma unroll
  for (int ee = 0; ee < NE; ++ee) {
    unsigned long long m = __ballot(e == ee);
    if (e == ee) {
      int leader = __ffsll((long long)m) - 1;
      int cnt = __popcll(m);
      int start = 0;
      if (lane == leader) start = atomicAdd(&g_cursor[ee], cnt);
      start = __shfl(start, leader, 64);
      pos = start + __popcll(m & (lanebit - 1));
    }
  }
  int sl = base[e] + pos;
  bucket_tok[sl] = gid >> 1;
  bucket_v[sl]   = tok_v[gid];
  slot_of[gid]   = sl;
  if (gid < NE) g_base[gid] = base[gid];
}

// ------------------- GEMM1: h = v * silu(x_rows @ WfcT) --------------------
// 1-D grid, XCD-swizzled: xcd = id&7; nt iterates fastest within one XCD so
// all 16 n-tiles sharing an A-panel hit the same per-XCD L2.
__global__ __launch_bounds__(256) void gemm1_kernel(
    const unsigned short* __restrict__ xb, const unsigned short* __restrict__ wfcp,
    const int* __restrict__ g_counts, const int* __restrict__ g_base,
    const int* __restrict__ bucket_tok, const float* __restrict__ bucket_v,
    unsigned short* __restrict__ hbuf)
{
  int id = blockIdx.x;
  int xcd = id & 7;
  int r = id >> 3;
  int nt = r & 15;                 // HD/128 = 16 n-tiles, fastest per XCD
  int g = (r >> 4) * 8 + xcd;      // (e,mt) group pinned to this XCD, [0,160)
  int e = g / MTILES, mt = g % MTILES;

  int cnt = g_counts[e];
  int m0 = mt * 128;
  if (m0 >= cnt) return;
  int base = g_base[e];
  int n0 = nt * 128;

  __shared__ __align__(16) unsigned short lsA[128 * 32];
  __shared__ __align__(16) unsigned short lsB[128 * 32];
  __shared__ int   s_tok[128];
  __shared__ float s_v[128];

  int t = threadIdx.x;
  if (t < 128) {
    int ok = (m0 + t) < cnt;
    s_tok[t] = ok ? bucket_tok[base + m0 + t] : 0;
    s_v[t]   = ok ? bucket_v[base + m0 + t] : 0.0f;
  }
  __syncthreads();

  int slot = t & 3;
  int r0 = t >> 2, r1 = r0 + 64;              // each thread stages 2 rows x 16B
  int gc0 = slot ^ ((r0 >> 1) & 3);
  int gc1 = slot ^ ((r1 >> 1) & 3);
  const unsigned short* gA0 = xb + (size_t)s_tok[r0] * CD + gc0 * 8;
  const unsigned short* gA1 = xb + (size_t)s_tok[r1] * CD + gc1 * 8;
  const unsigned short* gB0 = wfcp + ((size_t)e * HD + n0 + r0) * CD + gc0 * 8;
  const unsigned short* gB1 = wfcp + ((size_t)e * HD + n0 + r1) * CD + gc1 * 8;
  unsigned short* lA0 = &lsA[(size_t)t * 8];
  unsigned short* lA1 = &lsA[(size_t)(256 + t) * 8];
  unsigned short* lB0 = &lsB[(size_t)t * 8];
  unsigned short* lB1 = &lsB[(size_t)(256 + t) * 8];

  int lane = t & 63, wv = t >> 6;
  int wm = (wv & 1) * 64, wn = (wv >> 1) * 64;
  int ml = lane & 15, kq = lane >> 4;

  f32x4_t acc[4][4];
  #pragma unroll
  for (int i = 0; i < 4; ++i)
    #pragma unroll
    for (int j = 0; j < 4; ++j) acc[i][j] = (f32x4_t){0.f, 0.f, 0.f, 0.f};

  for (int k0 = 0; k0 < CD; k0 += 32) {
    __syncthreads();
    gl2lds16(gA0 + k0, lA0);
    gl2lds16(gA1 + k0, lA1);
    gl2lds16(gB0 + k0, lB0);
    gl2lds16(gB1 + k0, lB1);
    __syncthreads();
    short8_t af[4], bfr[4];
    #pragma unroll
    for (int i = 0; i < 4; ++i) {
      af[i]  = *(const short8_t*)&lsA[swz(wm + i * 16 + ml, kq) * 8];
      bfr[i] = *(const short8_t*)&lsB[swz(wn + i * 16 + ml, kq) * 8];
    }
    #pragma unroll
    for (int i = 0; i < 4; ++i)
      #pragma unroll
      for (int j = 0; j < 4; ++j)
        acc[i][j] = __builtin_amdgcn_mfma_f32_16x16x32_bf16(
            FragArg{af[i]}, FragArg{bfr[j]}, acc[i][j], 0, 0, 0);
  }

  #pragma unroll
  for (int i = 0; i < 4; ++i) {
    int rb = wm + i * 16 + kq * 4;
    #pragma unroll
    for (int r2 = 0; r2 < 4; ++r2) {
      int row = rb + r2;
      if (m0 + row < cnt) {
        float v = s_v[row];
        size_t ro = (size_t)(base + m0 + row) * HD + n0;
        #pragma unroll
        for (int j = 0; j < 4; ++j) {
          float z = acc[i][j][r2];
          float val = v * (z / (1.0f + __expf(-z)));   // gate_w * silu(z)
          hbuf[ro + wn + j * 16 + ml] = f2b(val);
        }
      }
    }
  }
}

// ------------------- GEMM2: o_slot = h_rows @ WprojT -----------------------
__global__ __launch_bounds__(256) void gemm2_kernel(
    const unsigned short* __restrict__ hbuf, const unsigned short* __restrict__ wpjp,
    const int* __restrict__ g_counts, const int* __restrict__ g_base,
    unsigned short* __restrict__ oslot)
{
  int id = blockIdx.x;
  int xcd = id & 7;
  int r = id >> 3;
  int nt = r & 7;                  // CD/128 = 8 n-tiles, fastest per XCD
  int g = (r >> 3) * 8 + xcd;      // [0,160)
  int e = g / MTILES, mt = g % MTILES;

  int cnt = g_counts[e];
  int m0 = mt * 128;
  if (m0 >= cnt) return;
  int base = g_base[e];
  int n0 = nt * 128;

  __shared__ __align__(16) unsigned short lsA[128 * 32];
  __shared__ __align__(16) unsigned short lsB[128 * 32];

  int t = threadIdx.x;
  int slot = t & 3;
  int r0 = t >> 2, r1 = r0 + 64;
  int gc0 = slot ^ ((r0 >> 1) & 3);
  int gc1 = slot ^ ((r1 >> 1) & 3);
  // Padded rows may over-read past hbuf into the oslot region (inside d_ws);
  // their stores are guarded below.
  const unsigned short* gA0 = hbuf + (size_t)(base + m0 + r0) * HD + gc0 * 8;
  const unsigned short* gA1 = hbuf + (size_t)(base + m0 + r1) * HD + gc1 * 8;
  const unsigned short* gB0 = wpjp + ((size_t)e * CD + n0 + r0) * HD + gc0 * 8;
  const unsigned short* gB1 = wpjp + ((size_t)e * CD + n0 + r1) * HD + gc1 * 8;
  unsigned short* lA0 = &lsA[(size_t)t * 8];
  unsigned short* lA1 = &lsA[(size_t)(256 + t) * 8];
  unsigned short* lB0 = &lsB[(size_t)t * 8];
  unsigned short* lB1 = &lsB[(size_t)(256 + t) * 8];

  int lane = t & 63, wv = t >> 6;
  int wm = (wv & 1) * 64, wn = (wv >> 1) * 64;
  int ml = lane & 15, kq = lane >> 4;

  f32x4_t acc[4][4];
  #pragma unroll
  for (int i = 0; i < 4; ++i)
    #pragma unroll
    for (int j = 0; j < 4; ++j) acc[i][j] = (f32x4_t){0.f, 0.f, 0.f, 0.f};

  for (int k0 = 0; k0 < HD; k0 += 32) {
    __syncthreads();
    gl2lds16(gA0 + k0, lA0);
    gl2lds16(gA1 + k0, lA1);
    gl2lds16(gB0 + k0, lB0);
    gl2lds16(gB1 + k0, lB1);
    __syncthreads();
    short8_t af[4], bfr[4];
    #pragma unroll
    for (int i = 0; i < 4; ++i) {
      af[i]  = *(const short8_t*)&lsA[swz(wm + i * 16 + ml, kq) * 8];
      bfr[i] = *(const short8_t*)&lsB[swz(wn + i * 16 + ml, kq) * 8];
    }
    #pragma unroll
    for (int i = 0; i < 4; ++i)
      #pragma unroll
      for (int j = 0; j < 4; ++j)
        acc[i][j] = __builtin_amdgcn_mfma_f32_16x16x32_bf16(
            FragArg{af[i]}, FragArg{bfr[j]}, acc[i][j], 0, 0, 0);
  }

  #pragma unroll
  for (int i = 0; i < 4; ++i) {
    int rb = wm + i * 16 + kq * 4;
    #pragma unroll
    for (int r2 = 0; r2 < 4; ++r2) {
      int row = rb + r2;
      if (m0 + row < cnt) {
        size_t ro = (size_t)(base + m0 + row) * CD + n0;
        #pragma unroll
        for (int j = 0; j < 4; ++j)
          oslot[ro + wn + j * 16 + ml] = f2b(acc[i][j][r2]);
      }
    }
  }
}

// ----------- combine: out[t] = fp32(oslot[s0]) + fp32(oslot[s1]) -----------
__global__ __launch_bounds__(256) void combine_kernel(
    const unsigned short* __restrict__ oslot, const int* __restrict__ slot_of,
    float* __restrict__ out)
{
  int gid = blockIdx.x * 256 + threadIdx.x;
  int tk = gid >> 7;               // 128 chunks of 8 per token
  int ch = (gid & 127) * 8;
  int s0 = slot_of[tk * 2], s1 = slot_of[tk * 2 + 1];
  short8_t a = *(const short8_t*)(oslot + (size_t)s0 * CD + ch);
  short8_t b = *(const short8_t*)(oslot + (size_t)s1 * CD + ch);
  float* op = out + (size_t)tk * CD + ch;
  float4 o0, o1;
  o0.x = b2f((unsigned short)a[0]) + b2f((unsigned short)b[0]);
  o0.y = b2f((unsigned short)a[1]) + b2f((unsigned short)b[1]);
  o0.z = b2f((unsigned short)a[2]) + b2f((unsigned short)b[2]);
  o0.w = b2f((unsigned short)a[3]) + b2f((unsigned short)b[3]);
  o1.x = b2f((unsigned short)a[4]) + b2f((unsigned short)b[4]);
  o1.y = b2f((unsigned short)a[5]) + b2f((unsigned short)b[5]);
  o1.z = b2f((unsigned short)a[6]) + b2f((unsigned short)b[6]);
  o1.w = b2f((unsigned short)a[7]) + b2f((unsigned short)b[7]);
  *(float4*)op = o0;
  *(float4*)(op + 4) = o1;
}

// ---------------------------------------------------------------------------
extern "C" void kernel_launch(void* const* d_in, const int* in_sizes, int n_in,
                              void* d_out, int out_size, void* d_ws, size_t ws_size,
                              hipStream_t stream)
{
  const float* x   = (const float*)d_in[0];
  const float* wg  = (const float*)d_in[1];
  const float* wfc = (const float*)d_in[2];
  const float* wpj = (const float*)d_in[3];
  float* out = (float*)d_out;

  // workspace carve-up (~185 MB). hbuf precedes oslot so padded-tile A
  // over-reads in gemm2 stay inside d_ws.
  char* w = (char*)d_ws;
  unsigned short* wfcp  = (unsigned short*)w; w += (size_t)NE * HD * CD * 2;  // 33.5 MB
  unsigned short* wpjp  = (unsigned short*)w; w += (size_t)NE * CD * HD * 2;  // 33.5 MB
  unsigned short* xb    = (unsigned short*)w; w += (size_t)NTOK * CD * 2;     // 16.8 MB
  unsigned short* hbuf  = (unsigned short*)w; w += (size_t)NSLOT * HD * 2;    // 67.1 MB
  unsigned short* oslot = (unsigned short*)w; w += (size_t)NSLOT * CD * 2;    // 33.5 MB
  int*   tok_e      = (int*)w;   w += NSLOT * 4;
  float* tok_v      = (float*)w; w += NSLOT * 4;
  int*   slot_of    = (int*)w;   w += NSLOT * 4;
  int*   bucket_tok = (int*)w;   w += NSLOT * 4;
  float* bucket_v   = (float*)w; w += NSLOT * 4;
  int*   g_counts   = (int*)w;   w += NE * 4;   // contiguous with g_cursor:
  int*   g_cursor   = (int*)w;   w += NE * 4;   // one 64B memset covers both
  int*   g_base     = (int*)w;   w += 256;

  hipMemsetAsync(g_counts, 0, 2 * NE * sizeof(int), stream);
  prep_kernel<<<GATE_BLOCKS + 4096, 256, 0, stream>>>(
      x, wg, wfc, wpj, xb, wfcp, wpjp, tok_e, tok_v, g_counts);
  scatter_kernel<<<NSLOT / 256, 256, 0, stream>>>(
      tok_e, tok_v, g_counts, g_cursor, g_base, bucket_tok, bucket_v, slot_of);
  gemm1_kernel<<<(HD / 128) * MTILES * NE, 256, 0, stream>>>(
      xb, wfcp, g_counts, g_base, bucket_tok, bucket_v, hbuf);
  gemm2_kernel<<<(CD / 128) * MTILES * NE, 256, 0, stream>>>(
      hbuf, wpjp, g_counts, g_base, oslot);
  combine_kernel<<<(NTOK * CD / 8) / 256, 256, 0, stream>>>(oslot, slot_of, out);
}

// Round 5
// 454.275 us; speedup vs baseline: 1.0966x; 1.0268x over previous
//
#include <hip/hip_runtime.h>
#include <hip/hip_bf16.h>

// ---------------------------------------------------------------------------
// MoE (top-2 of 8 experts), B=4 T=2048 C=1024 H=2048 E=8. FP32 in/out;
// internal GEMMs in bf16 MFMA. Round 5: BK=64 K-loop (half the barrier
// drains; 33 KB LDS keeps ~4 blocks/CU) + expert-per-XCD mapping (id&7 = e,
// one expert's B-panel resident per XCD L2). Prep/scatter/combine unchanged.
// ---------------------------------------------------------------------------

#define NTOK 8192
#define CD   1024
#define HD   2048
#define NE   8
#define NSLOT 16384   // NTOK * top_k
#define MTILES 20     // supports up to 2560 tokens per expert (mean 2048, 12 sigma)
#define BK   64

typedef short  short4_t  __attribute__((ext_vector_type(4)));
typedef short  short8_t  __attribute__((ext_vector_type(8)));
typedef __bf16 bf16x8_t  __attribute__((ext_vector_type(8)));
typedef float  f32x4_t   __attribute__((ext_vector_type(4)));

// MFMA builtin arg-type shim: satisfies either V8s or V8bf16 signatures.
struct FragArg {
  short8_t v;
  __device__ operator short8_t() const { return v; }
  __device__ operator bf16x8_t() const { return __builtin_bit_cast(bf16x8_t, v); }
};

static __device__ __forceinline__ float b2f(unsigned short u) {
  union { float f; unsigned int i; } w; w.i = ((unsigned int)u) << 16; return w.f;
}
static __device__ __forceinline__ unsigned short f2b(float f) {
  unsigned int u = __float_as_uint(f);
  u += 0x7fffu + ((u >> 16) & 1u);           // round-to-nearest-even
  return (unsigned short)(u >> 16);
}
static __device__ __forceinline__ void gl2lds16(const void* g, void* l) {
  __builtin_amdgcn_global_load_lds((__attribute__((address_space(1))) void*)g,
                                   (__attribute__((address_space(3))) void*)l,
                                   16, 0, 0);
}
// BK=64 XOR swizzle: row has 8 16B-chunks; chunk gc lives at slot gc^f(row),
// f(row)=(row>>1)&7. Staging lane kc loads gc=kc^f(row); fragment read of
// chunk c hits slot c^f(row). 16-lane reads: 8 residues x2 -> 2-way (free).

// ---- fused prep: blocks [0,2048) = gate(+x->bf16, +histogram);
//      blocks [2048,6144) = weight pack fp32 (D0,D1,8) -> bf16 (8,D1,D0) ----
#define GATE_BLOCKS (NTOK / 4)
__global__ __launch_bounds__(256) void prep_kernel(
    const float* __restrict__ x, const float* __restrict__ wg,
    const float* __restrict__ wfc, const float* __restrict__ wpj,
    unsigned short* __restrict__ xb,
    unsigned short* __restrict__ wfcp, unsigned short* __restrict__ wpjp,
    int* __restrict__ tok_e, float* __restrict__ tok_v,
    int* __restrict__ g_counts)
{
  __shared__ __align__(16) unsigned short lds[NE * 32 * 40];  // pack role
  __shared__ int hist[NE];                                    // gate role
  int t = threadIdx.x;

  if (blockIdx.x < GATE_BLOCKS) {
    // ---------------- gate role: one wave per token ----------------
    if (t < NE) hist[t] = 0;
    __syncthreads();
    int wv = t >> 6, lane = t & 63;
    int tk = blockIdx.x * 4 + wv;
    const float* xr = x + (size_t)tk * CD;
    unsigned short* xbr = xb + (size_t)tk * CD;
    float acc[NE] = {0, 0, 0, 0, 0, 0, 0, 0};
    #pragma unroll
    for (int jj = 0; jj < 4; ++jj) {
      int c0 = (lane + 64 * jj) * 4;
      float4 xv = *(const float4*)(xr + c0);
      short4_t ob;                             // fused fp32->bf16 of x
      ob[0] = (short)f2b(xv.x); ob[1] = (short)f2b(xv.y);
      ob[2] = (short)f2b(xv.z); ob[3] = (short)f2b(xv.w);
      *(short4_t*)(xbr + c0) = ob;
      #pragma unroll
      for (int j = 0; j < 4; ++j) {
        float xf = (j == 0) ? xv.x : (j == 1) ? xv.y : (j == 2) ? xv.z : xv.w;
        const float* wr = wg + (size_t)(c0 + j) * NE;
        float4 w0 = *(const float4*)wr;
        float4 w1 = *(const float4*)(wr + 4);
        acc[0] += xf * w0.x; acc[1] += xf * w0.y;
        acc[2] += xf * w0.z; acc[3] += xf * w0.w;
        acc[4] += xf * w1.x; acc[5] += xf * w1.y;
        acc[6] += xf * w1.z; acc[7] += xf * w1.w;
      }
    }
    #pragma unroll
    for (int off = 32; off >= 1; off >>= 1)
      #pragma unroll
      for (int e = 0; e < NE; ++e) acc[e] += __shfl_down(acc[e], off, 64);
    if (lane == 0) {
      float v1 = -3.0e38f, v2 = -3.0e38f; int i1 = 0, i2 = 1;
      #pragma unroll
      for (int e = 0; e < NE; ++e) {          // strict '>' => ties keep lower idx
        float g = acc[e];
        if (g > v1) { v2 = v1; i2 = i1; v1 = g; i1 = e; }
        else if (g > v2) { v2 = g; i2 = e; }
      }
      tok_e[tk * 2] = i1; tok_e[tk * 2 + 1] = i2;
      tok_v[tk * 2] = v1; tok_v[tk * 2 + 1] = v2;
      atomicAdd(&hist[i1], 1); atomicAdd(&hist[i2], 1);
    }
    __syncthreads();
    if (t < NE && hist[t] > 0) atomicAdd(&g_counts[t], hist[t]);
  } else {
    // ---------------- pack role ----------------
    int pid = blockIdx.x - GATE_BLOCKS;       // [0, 4096)
    int tensor = pid >> 11;                   // 2048 blocks per tensor
    int rem = pid & 2047;
    int bx = rem & 63, by = rem >> 6;         // 64 x 32 tile grid
    const float* in; unsigned short* out; int D0, D1, b0, b1;
    if (tensor == 0) { in = wfc; out = wfcp; D0 = CD; D1 = HD;
                       b1 = bx * 32; b0 = by * 32; }
    else             { in = wpj; out = wpjp; D0 = HD; D1 = CD;
                       b1 = by * 32; b0 = bx * 32; }
    int d1i = t & 31, d0q = t >> 5;
    #pragma unroll
    for (int r = 0; r < 4; ++r) {
      int d0i = d0q * 4 + r;
      const float* src = in + ((size_t)(b0 + d0i) * D1 + (b1 + d1i)) * NE;
      float4 v0 = *(const float4*)src;
      float4 v1 = *(const float4*)(src + 4);
      unsigned short* dst0 = &lds[d1i * 40 + d0i];
      dst0[0 * 32 * 40] = f2b(v0.x);
      dst0[1 * 32 * 40] = f2b(v0.y);
      dst0[2 * 32 * 40] = f2b(v0.z);
      dst0[3 * 32 * 40] = f2b(v0.w);
      dst0[4 * 32 * 40] = f2b(v1.x);
      dst0[5 * 32 * 40] = f2b(v1.y);
      dst0[6 * 32 * 40] = f2b(v1.z);
      dst0[7 * 32 * 40] = f2b(v1.w);
    }
    __syncthreads();
    int dchunk = t & 3, d1w = (t >> 2) & 31, ehalf = t >> 7;
    #pragma unroll
    for (int p = 0; p < 4; ++p) {
      int e = ehalf + 2 * p;
      short8_t v = *(const short8_t*)&lds[e * 32 * 40 + d1w * 40 + dchunk * 8];
      *(short8_t*)(out + ((size_t)e * D1 + (b1 + d1w)) * D0 + b0 + dchunk * 8) = v;
    }
  }
}

// ------ scatter: 64 blocks, wave-aggregated atomics on g_cursor ------------
__global__ __launch_bounds__(256) void scatter_kernel(
    const int* __restrict__ tok_e, const float* __restrict__ tok_v,
    const int* __restrict__ g_counts, int* __restrict__ g_cursor,
    int* __restrict__ g_base,
    int* __restrict__ bucket_tok, float* __restrict__ bucket_v,
    int* __restrict__ slot_of)
{
  int gid = blockIdx.x * 256 + threadIdx.x;   // 16384 threads, 1 slot each
  int lane = threadIdx.x & 63;
  int base[NE];
  { int o = 0;
    #pragma unroll
    for (int e = 0; e < NE; ++e) { base[e] = o; o += g_counts[e]; } }
  int e = tok_e[gid];
  unsigned long long lanebit = 1ull << lane;
  int pos = 0;
  #pragma unroll
  for (int ee = 0; ee < NE; ++ee) {
    unsigned long long m = __ballot(e == ee);
    if (e == ee) {
      int leader = __ffsll((long long)m) - 1;
      int cnt = __popcll(m);
      int start = 0;
      if (lane == leader) start = atomicAdd(&g_cursor[ee], cnt);
      start = __shfl(start, leader, 64);
      pos = start + __popcll(m & (lanebit - 1));
    }
  }
  int sl = base[e] + pos;
  bucket_tok[sl] = gid >> 1;
  bucket_v[sl]   = tok_v[gid];
  slot_of[gid]   = sl;
  if (gid < NE) g_base[gid] = base[gid];
}

// ------------------- GEMM1: h = v * silu(x_rows @ WfcT) --------------------
// id&7 = expert = XCD (one expert's B-panel L2-resident per XCD); nt fastest.
__global__ __launch_bounds__(256) void gemm1_kernel(
    const unsigned short* __restrict__ xb, const unsigned short* __restrict__ wfcp,
    const int* __restrict__ g_counts, const int* __restrict__ g_base,
    const int* __restrict__ bucket_tok, const float* __restrict__ bucket_v,
    unsigned short* __restrict__ hbuf)
{
  int id = blockIdx.x;
  int e = id & 7;
  int r = id >> 3;
  int nt = r & 15;                 // HD/128 = 16 n-tiles, fastest
  int mt = r >> 4;                 // [0, MTILES)

  int cnt = g_counts[e];
  int m0 = mt * 128;
  if (m0 >= cnt) return;
  int base = g_base[e];
  int n0 = nt * 128;

  __shared__ __align__(16) unsigned short lsA[128 * BK];
  __shared__ __align__(16) unsigned short lsB[128 * BK];
  __shared__ int   s_tok[128];
  __shared__ float s_v[128];

  int t = threadIdx.x;
  if (t < 128) {
    int ok = (m0 + t) < cnt;
    s_tok[t] = ok ? bucket_tok[base + m0 + t] : 0;
    s_v[t]   = ok ? bucket_v[base + m0 + t] : 0.0f;
  }
  __syncthreads();

  int lane = t & 63, wv = t >> 6;
  int subrow = lane >> 3, kc = lane & 7;
  // staging: pass p covers rows p*32 + wv*8 .. +7; lane -> (row, kc) chunk
  const unsigned short* pA[4]; const unsigned short* pB[4];
  unsigned short* dA[4]; unsigned short* dB[4];
  #pragma unroll
  for (int p = 0; p < 4; ++p) {
    int rr = p * 32 + wv * 8 + subrow;
    int gc = kc ^ ((rr >> 1) & 7);
    pA[p] = xb + (size_t)s_tok[rr] * CD + gc * 8;
    pB[p] = wfcp + ((size_t)e * HD + n0 + rr) * CD + gc * 8;
    dA[p] = &lsA[(p * 32 + wv * 8) * BK];     // wave-uniform base; HW adds lane*16
    dB[p] = &lsB[(p * 32 + wv * 8) * BK];
  }

  int wm = (wv & 1) * 64, wn = (wv >> 1) * 64;
  int ml = lane & 15, kq = lane >> 4;

  f32x4_t acc[4][4];
  #pragma unroll
  for (int i = 0; i < 4; ++i)
    #pragma unroll
    for (int j = 0; j < 4; ++j) acc[i][j] = (f32x4_t){0.f, 0.f, 0.f, 0.f};

  for (int k0 = 0; k0 < CD; k0 += BK) {
    __syncthreads();
    #pragma unroll
    for (int p = 0; p < 4; ++p) {
      gl2lds16(pA[p], dA[p]); pA[p] += BK;
      gl2lds16(pB[p], dB[p]); pB[p] += BK;
    }
    __syncthreads();
    #pragma unroll
    for (int s = 0; s < 2; ++s) {
      short8_t af[4], bfr[4];
      #pragma unroll
      for (int i = 0; i < 4; ++i) {
        int ar = wm + i * 16 + ml;
        af[i]  = *(const short8_t*)&lsA[ar * BK + (((s * 4 + kq) ^ ((ar >> 1) & 7)) * 8)];
        int br = wn + i * 16 + ml;
        bfr[i] = *(const short8_t*)&lsB[br * BK + (((s * 4 + kq) ^ ((br >> 1) & 7)) * 8)];
      }
      #pragma unroll
      for (int i = 0; i < 4; ++i)
        #pragma unroll
        for (int j = 0; j < 4; ++j)
          acc[i][j] = __builtin_amdgcn_mfma_f32_16x16x32_bf16(
              FragArg{af[i]}, FragArg{bfr[j]}, acc[i][j], 0, 0, 0);
    }
  }

  #pragma unroll
  for (int i = 0; i < 4; ++i) {
    int rb = wm + i * 16 + kq * 4;
    #pragma unroll
    for (int r2 = 0; r2 < 4; ++r2) {
      int row = rb + r2;
      if (m0 + row < cnt) {
        float v = s_v[row];
        size_t ro = (size_t)(base + m0 + row) * HD + n0;
        #pragma unroll
        for (int j = 0; j < 4; ++j) {
          float z = acc[i][j][r2];
          float val = v * (z / (1.0f + __expf(-z)));   // gate_w * silu(z)
          hbuf[ro + wn + j * 16 + ml] = f2b(val);
        }
      }
    }
  }
}

// ------------------- GEMM2: o_slot = h_rows @ WprojT -----------------------
__global__ __launch_bounds__(256) void gemm2_kernel(
    const unsigned short* __restrict__ hbuf, const unsigned short* __restrict__ wpjp,
    const int* __restrict__ g_counts, const int* __restrict__ g_base,
    unsigned short* __restrict__ oslot)
{
  int id = blockIdx.x;
  int e = id & 7;
  int r = id >> 3;
  int nt = r & 7;                  // CD/128 = 8 n-tiles, fastest
  int mt = r >> 3;                 // [0, MTILES)

  int cnt = g_counts[e];
  int m0 = mt * 128;
  if (m0 >= cnt) return;
  int base = g_base[e];
  int n0 = nt * 128;

  __shared__ __align__(16) unsigned short lsA[128 * BK];
  __shared__ __align__(16) unsigned short lsB[128 * BK];

  int t = threadIdx.x;
  int lane = t & 63, wv = t >> 6;
  int subrow = lane >> 3, kc = lane & 7;
  // Padded rows over-read past hbuf into oslot region (inside d_ws); their
  // stores are guarded below.
  const unsigned short* pA[4]; const unsigned short* pB[4];
  unsigned short* dA[4]; unsigned short* dB[4];
  #pragma unroll
  for (int p = 0; p < 4; ++p) {
    int rr = p * 32 + wv * 8 + subrow;
    int gc = kc ^ ((rr >> 1) & 7);
    pA[p] = hbuf + ((size_t)(base + m0 + rr)) * HD + gc * 8;
    pB[p] = wpjp + ((size_t)e * CD + n0 + rr) * HD + gc * 8;
    dA[p] = &lsA[(p * 32 + wv * 8) * BK];
    dB[p] = &lsB[(p * 32 + wv * 8) * BK];
  }

  int wm = (wv & 1) * 64, wn = (wv >> 1) * 64;
  int ml = lane & 15, kq = lane >> 4;

  f32x4_t acc[4][4];
  #pragma unroll
  for (int i = 0; i < 4; ++i)
    #pragma unroll
    for (int j = 0; j < 4; ++j) acc[i][j] = (f32x4_t){0.f, 0.f, 0.f, 0.f};

  for (int k0 = 0; k0 < HD; k0 += BK) {
    __syncthreads();
    #pragma unroll
    for (int p = 0; p < 4; ++p) {
      gl2lds16(pA[p], dA[p]); pA[p] += BK;
      gl2lds16(pB[p], dB[p]); pB[p] += BK;
    }
    __syncthreads();
    #pragma unroll
    for (int s = 0; s < 2; ++s) {
      short8_t af[4], bfr[4];
      #pragma unroll
      for (int i = 0; i < 4; ++i) {
        int ar = wm + i * 16 + ml;
        af[i]  = *(const short8_t*)&lsA[ar * BK + (((s * 4 + kq) ^ ((ar >> 1) & 7)) * 8)];
        int br = wn + i * 16 + ml;
        bfr[i] = *(const short8_t*)&lsB[br * BK + (((s * 4 + kq) ^ ((br >> 1) & 7)) * 8)];
      }
      #pragma unroll
      for (int i = 0; i < 4; ++i)
        #pragma unroll
        for (int j = 0; j < 4; ++j)
          acc[i][j] = __builtin_amdgcn_mfma_f32_16x16x32_bf16(
              FragArg{af[i]}, FragArg{bfr[j]}, acc[i][j], 0, 0, 0);
    }
  }

  #pragma unroll
  for (int i = 0; i < 4; ++i) {
    int rb = wm + i * 16 + kq * 4;
    #pragma unroll
    for (int r2 = 0; r2 < 4; ++r2) {
      int row = rb + r2;
      if (m0 + row < cnt) {
        size_t ro = (size_t)(base + m0 + row) * CD + n0;
        #pragma unroll
        for (int j = 0; j < 4; ++j)
          oslot[ro + wn + j * 16 + ml] = f2b(acc[i][j][r2]);
      }
    }
  }
}

// ----------- combine: out[t] = fp32(oslot[s0]) + fp32(oslot[s1]) -----------
__global__ __launch_bounds__(256) void combine_kernel(
    const unsigned short* __restrict__ oslot, const int* __restrict__ slot_of,
    float* __restrict__ out)
{
  int gid = blockIdx.x * 256 + threadIdx.x;
  int tk = gid >> 7;               // 128 chunks of 8 per token
  int ch = (gid & 127) * 8;
  int s0 = slot_of[tk * 2], s1 = slot_of[tk * 2 + 1];
  short8_t a = *(const short8_t*)(oslot + (size_t)s0 * CD + ch);
  short8_t b = *(const short8_t*)(oslot + (size_t)s1 * CD + ch);
  float* op = out + (size_t)tk * CD + ch;
  float4 o0, o1;
  o0.x = b2f((unsigned short)a[0]) + b2f((unsigned short)b[0]);
  o0.y = b2f((unsigned short)a[1]) + b2f((unsigned short)b[1]);
  o0.z = b2f((unsigned short)a[2]) + b2f((unsigned short)b[2]);
  o0.w = b2f((unsigned short)a[3]) + b2f((unsigned short)b[3]);
  o1.x = b2f((unsigned short)a[4]) + b2f((unsigned short)b[4]);
  o1.y = b2f((unsigned short)a[5]) + b2f((unsigned short)b[5]);
  o1.z = b2f((unsigned short)a[6]) + b2f((unsigned short)b[6]);
  o1.w = b2f((unsigned short)a[7]) + b2f((unsigned short)b[7]);
  *(float4*)op = o0;
  *(float4*)(op + 4) = o1;
}

// ---------------------------------------------------------------------------
extern "C" void kernel_launch(void* const* d_in, const int* in_sizes, int n_in,
                              void* d_out, int out_size, void* d_ws, size_t ws_size,
                              hipStream_t stream)
{
  const float* x   = (const float*)d_in[0];
  const float* wg  = (const float*)d_in[1];
  const float* wfc = (const float*)d_in[2];
  const float* wpj = (const float*)d_in[3];
  float* out = (float*)d_out;

  // workspace carve-up (~185 MB). hbuf precedes oslot so padded-tile A
  // over-reads in gemm2 stay inside d_ws.
  char* w = (char*)d_ws;
  unsigned short* wfcp  = (unsigned short*)w; w += (size_t)NE * HD * CD * 2;  // 33.5 MB
  unsigned short* wpjp  = (unsigned short*)w; w += (size_t)NE * CD * HD * 2;  // 33.5 MB
  unsigned short* xb    = (unsigned short*)w; w += (size_t)NTOK * CD * 2;     // 16.8 MB
  unsigned short* hbuf  = (unsigned short*)w; w += (size_t)NSLOT * HD * 2;    // 67.1 MB
  unsigned short* oslot = (unsigned short*)w; w += (size_t)NSLOT * CD * 2;    // 33.5 MB
  int*   tok_e      = (int*)w;   w += NSLOT * 4;
  float* tok_v      = (float*)w; w += NSLOT * 4;
  int*   slot_of    = (int*)w;   w += NSLOT * 4;
  int*   bucket_tok = (int*)w;   w += NSLOT * 4;
  float* bucket_v   = (float*)w; w += NSLOT * 4;
  int*   g_counts   = (int*)w;   w += NE * 4;   // contiguous with g_cursor:
  int*   g_cursor   = (int*)w;   w += NE * 4;   // one 64B memset covers both
  int*   g_base     = (int*)w;   w += 256;

  hipMemsetAsync(g_counts, 0, 2 * NE * sizeof(int), stream);
  prep_kernel<<<GATE_BLOCKS + 4096, 256, 0, stream>>>(
      x, wg, wfc, wpj, xb, wfcp, wpjp, tok_e, tok_v, g_counts);
  scatter_kernel<<<NSLOT / 256, 256, 0, stream>>>(
      tok_e, tok_v, g_counts, g_cursor, g_base, bucket_tok, bucket_v, slot_of);
  gemm1_kernel<<<(HD / 128) * MTILES * NE, 256, 0, stream>>>(
      xb, wfcp, g_counts, g_base, bucket_tok, bucket_v, hbuf);
  gemm2_kernel<<<(CD / 128) * MTILES * NE, 256, 0, stream>>>(
      hbuf, wpjp, g_counts, g_base, oslot);
  combine_kernel<<<(NTOK * CD / 8) / 256, 256, 0, stream>>>(oslot, slot_of, out);
}

// Round 6
// 451.887 us; speedup vs baseline: 1.1024x; 1.0053x over previous
//
#include <hip/hip_runtime.h>
#include <hip/hip_bf16.h>

// ---------------------------------------------------------------------------
// MoE (top-2 of 8 experts), B=4 T=2048 C=1024 H=2048 E=8. FP32 in/out;
// internal GEMMs in bf16 MFMA. Round 6: wpj weight-pack moved INTO the gemm1
// dispatch (blocks [0,2048) = pack role) — wpjp is only needed by gemm2, so
// its packing hides under gemm1's compute-bound blocks instead of occupying
// a serial prep stage. Prep = gate + pack-wfc only. GEMM structure = round 5
// (BK=64, expert-per-XCD, XOR-swizzled LDS, mfma_f32_16x16x32_bf16).
// ---------------------------------------------------------------------------

#define NTOK 8192
#define CD   1024
#define HD   2048
#define NE   8
#define NSLOT 16384   // NTOK * top_k
#define MTILES 20     // supports up to 2560 tokens per expert (mean 2048, 12 sigma)
#define BK   64
#define PACK_BLOCKS 2048   // 64 x 32 tile grid per weight tensor

typedef short  short4_t  __attribute__((ext_vector_type(4)));
typedef short  short8_t  __attribute__((ext_vector_type(8)));
typedef __bf16 bf16x8_t  __attribute__((ext_vector_type(8)));
typedef float  f32x4_t   __attribute__((ext_vector_type(4)));

// MFMA builtin arg-type shim: satisfies either V8s or V8bf16 signatures.
struct FragArg {
  short8_t v;
  __device__ operator short8_t() const { return v; }
  __device__ operator bf16x8_t() const { return __builtin_bit_cast(bf16x8_t, v); }
};

static __device__ __forceinline__ float b2f(unsigned short u) {
  union { float f; unsigned int i; } w; w.i = ((unsigned int)u) << 16; return w.f;
}
static __device__ __forceinline__ unsigned short f2b(float f) {
  unsigned int u = __float_as_uint(f);
  u += 0x7fffu + ((u >> 16) & 1u);           // round-to-nearest-even
  return (unsigned short)(u >> 16);
}
static __device__ __forceinline__ void gl2lds16(const void* g, void* l) {
  __builtin_amdgcn_global_load_lds((__attribute__((address_space(1))) void*)g,
                                   (__attribute__((address_space(3))) void*)l,
                                   16, 0, 0);
}

// ---- weight pack tile: fp32 (D0,D1,8) -> bf16 (8,D1,D0), one 32x32 tile ----
// smem must hold NE*32*40 unsigned shorts (20480 B).
static __device__ __forceinline__ void pack_tile(
    const float* __restrict__ in, unsigned short* __restrict__ out,
    int D0, int D1, int b0, int b1, unsigned short* smem, int t)
{
  int d1i = t & 31, d0q = t >> 5;
  #pragma unroll
  for (int r = 0; r < 4; ++r) {
    int d0i = d0q * 4 + r;
    const float* src = in + ((size_t)(b0 + d0i) * D1 + (b1 + d1i)) * NE;
    float4 v0 = *(const float4*)src;
    float4 v1 = *(const float4*)(src + 4);
    unsigned short* dst0 = &smem[d1i * 40 + d0i];
    dst0[0 * 32 * 40] = f2b(v0.x);
    dst0[1 * 32 * 40] = f2b(v0.y);
    dst0[2 * 32 * 40] = f2b(v0.z);
    dst0[3 * 32 * 40] = f2b(v0.w);
    dst0[4 * 32 * 40] = f2b(v1.x);
    dst0[5 * 32 * 40] = f2b(v1.y);
    dst0[6 * 32 * 40] = f2b(v1.z);
    dst0[7 * 32 * 40] = f2b(v1.w);
  }
  __syncthreads();
  int dchunk = t & 3, d1w = (t >> 2) & 31, ehalf = t >> 7;
  #pragma unroll
  for (int p = 0; p < 4; ++p) {
    int e = ehalf + 2 * p;
    short8_t v = *(const short8_t*)&smem[e * 32 * 40 + d1w * 40 + dchunk * 8];
    *(short8_t*)(out + ((size_t)e * D1 + (b1 + d1w)) * D0 + b0 + dchunk * 8) = v;
  }
}

// ---- prep: blocks [0,2048) = gate(+x->bf16, +histogram);
//      blocks [2048,4096) = pack wfc (C,H,E) -> wfcp (E,H,C) ----------------
#define GATE_BLOCKS (NTOK / 4)
__global__ __launch_bounds__(256) void prep_kernel(
    const float* __restrict__ x, const float* __restrict__ wg,
    const float* __restrict__ wfc,
    unsigned short* __restrict__ xb, unsigned short* __restrict__ wfcp,
    int* __restrict__ tok_e, float* __restrict__ tok_v,
    int* __restrict__ g_counts)
{
  __shared__ __align__(16) unsigned short lds[NE * 32 * 40];  // pack role
  __shared__ int hist[NE];                                    // gate role
  int t = threadIdx.x;

  if (blockIdx.x < GATE_BLOCKS) {
    // ---------------- gate role: one wave per token ----------------
    if (t < NE) hist[t] = 0;
    __syncthreads();
    int wv = t >> 6, lane = t & 63;
    int tk = blockIdx.x * 4 + wv;
    const float* xr = x + (size_t)tk * CD;
    unsigned short* xbr = xb + (size_t)tk * CD;
    float acc[NE] = {0, 0, 0, 0, 0, 0, 0, 0};
    #pragma unroll
    for (int jj = 0; jj < 4; ++jj) {
      int c0 = (lane + 64 * jj) * 4;
      float4 xv = *(const float4*)(xr + c0);
      short4_t ob;                             // fused fp32->bf16 of x
      ob[0] = (short)f2b(xv.x); ob[1] = (short)f2b(xv.y);
      ob[2] = (short)f2b(xv.z); ob[3] = (short)f2b(xv.w);
      *(short4_t*)(xbr + c0) = ob;
      #pragma unroll
      for (int j = 0; j < 4; ++j) {
        float xf = (j == 0) ? xv.x : (j == 1) ? xv.y : (j == 2) ? xv.z : xv.w;
        const float* wr = wg + (size_t)(c0 + j) * NE;
        float4 w0 = *(const float4*)wr;
        float4 w1 = *(const float4*)(wr + 4);
        acc[0] += xf * w0.x; acc[1] += xf * w0.y;
        acc[2] += xf * w0.z; acc[3] += xf * w0.w;
        acc[4] += xf * w1.x; acc[5] += xf * w1.y;
        acc[6] += xf * w1.z; acc[7] += xf * w1.w;
      }
    }
    #pragma unroll
    for (int off = 32; off >= 1; off >>= 1)
      #pragma unroll
      for (int e = 0; e < NE; ++e) acc[e] += __shfl_down(acc[e], off, 64);
    if (lane == 0) {
      float v1 = -3.0e38f, v2 = -3.0e38f; int i1 = 0, i2 = 1;
      #pragma unroll
      for (int e = 0; e < NE; ++e) {          // strict '>' => ties keep lower idx
        float g = acc[e];
        if (g > v1) { v2 = v1; i2 = i1; v1 = g; i1 = e; }
        else if (g > v2) { v2 = g; i2 = e; }
      }
      tok_e[tk * 2] = i1; tok_e[tk * 2 + 1] = i2;
      tok_v[tk * 2] = v1; tok_v[tk * 2 + 1] = v2;
      atomicAdd(&hist[i1], 1); atomicAdd(&hist[i2], 1);
    }
    __syncthreads();
    if (t < NE && hist[t] > 0) atomicAdd(&g_counts[t], hist[t]);
  } else {
    // ------------- pack wfc: D0=CD (by, 32 tiles), D1=HD (bx, 64) ----------
    int pid = blockIdx.x - GATE_BLOCKS;
    int bx = pid & 63, by = pid >> 6;
    pack_tile(wfc, wfcp, CD, HD, by * 32, bx * 32, lds, t);
  }
}

// ------ scatter: 64 blocks, wave-aggregated atomics on g_cursor ------------
__global__ __launch_bounds__(256) void scatter_kernel(
    const int* __restrict__ tok_e, const float* __restrict__ tok_v,
    const int* __restrict__ g_counts, int* __restrict__ g_cursor,
    int* __restrict__ g_base,
    int* __restrict__ bucket_tok, float* __restrict__ bucket_v,
    int* __restrict__ slot_of)
{
  int gid = blockIdx.x * 256 + threadIdx.x;   // 16384 threads, 1 slot each
  int lane = threadIdx.x & 63;
  int base[NE];
  { int o = 0;
    #pragma unroll
    for (int e = 0; e < NE; ++e) { base[e] = o; o += g_counts[e]; } }
  int e = tok_e[gid];
  unsigned long long lanebit = 1ull << lane;
  int pos = 0;
  #pragma unroll
  for (int ee = 0; ee < NE; ++ee) {
    unsigned long long m = __ballot(e == ee);
    if (e == ee) {
      int leader = __ffsll((long long)m) - 1;
      int cnt = __popcll(m);
      int start = 0;
      if (lane == leader) start = atomicAdd(&g_cursor[ee], cnt);
      start = __shfl(start, leader, 64);
      pos = start + __popcll(m & (lanebit - 1));
    }
  }
  int sl = base[e] + pos;
  bucket_tok[sl] = gid >> 1;
  bucket_v[sl]   = tok_v[gid];
  slot_of[gid]   = sl;
  if (gid < NE) g_base[gid] = base[gid];
}

// ------------------- GEMM1 (+ hidden wpj pack role) ------------------------
// blocks [0,2048): pack wpj (H,C,E) -> wpjp (E,C,H)  [consumed only by gemm2]
// blocks [2048,...): h = v * silu(x_rows @ WfcT); e=(id-2048)&7 -> XCD-pinned.
__global__ __launch_bounds__(256) void gemm1_kernel(
    const unsigned short* __restrict__ xb, const unsigned short* __restrict__ wfcp,
    const float* __restrict__ wpj, unsigned short* __restrict__ wpjp,
    const int* __restrict__ g_counts, const int* __restrict__ g_base,
    const int* __restrict__ bucket_tok, const float* __restrict__ bucket_v,
    unsigned short* __restrict__ hbuf)
{
  // one pool: gemm uses [0,8192) = lsA, [8192,16384) = lsB (shorts);
  // pack uses [0,10240).
  __shared__ __align__(16) unsigned short smem[128 * BK * 2];
  __shared__ int   s_tok[128];
  __shared__ float s_v[128];
  int t = threadIdx.x;

  if (blockIdx.x < PACK_BLOCKS) {
    // ------------- pack wpj: D0=HD (bx, 64 tiles), D1=CD (by, 32) ----------
    int pid = blockIdx.x;
    int bx = pid & 63, by = pid >> 6;
    pack_tile(wpj, wpjp, HD, CD, bx * 32, by * 32, smem, t);
    return;
  }

  int id = blockIdx.x - PACK_BLOCKS;
  int e = id & 7;
  int r = id >> 3;
  int nt = r & 15;                 // HD/128 = 16 n-tiles, fastest
  int mt = r >> 4;                 // [0, MTILES)

  int cnt = g_counts[e];
  int m0 = mt * 128;
  if (m0 >= cnt) return;
  int base = g_base[e];
  int n0 = nt * 128;

  unsigned short* lsA = smem;
  unsigned short* lsB = smem + 128 * BK;

  if (t < 128) {
    int ok = (m0 + t) < cnt;
    s_tok[t] = ok ? bucket_tok[base + m0 + t] : 0;
    s_v[t]   = ok ? bucket_v[base + m0 + t] : 0.0f;
  }
  __syncthreads();

  int lane = t & 63, wv = t >> 6;
  int subrow = lane >> 3, kc = lane & 7;
  // staging: pass p covers rows p*32 + wv*8 .. +7; lane -> (row, kc) chunk
  const unsigned short* pA[4]; const unsigned short* pB[4];
  unsigned short* dA[4]; unsigned short* dB[4];
  #pragma unroll
  for (int p = 0; p < 4; ++p) {
    int rr = p * 32 + wv * 8 + subrow;
    int gc = kc ^ ((rr >> 1) & 7);
    pA[p] = xb + (size_t)s_tok[rr] * CD + gc * 8;
    pB[p] = wfcp + ((size_t)e * HD + n0 + rr) * CD + gc * 8;
    dA[p] = &lsA[(p * 32 + wv * 8) * BK];     // wave-uniform base; HW adds lane*16
    dB[p] = &lsB[(p * 32 + wv * 8) * BK];
  }

  int wm = (wv & 1) * 64, wn = (wv >> 1) * 64;
  int ml = lane & 15, kq = lane >> 4;

  f32x4_t acc[4][4];
  #pragma unroll
  for (int i = 0; i < 4; ++i)
    #pragma unroll
    for (int j = 0; j < 4; ++j) acc[i][j] = (f32x4_t){0.f, 0.f, 0.f, 0.f};

  for (int k0 = 0; k0 < CD; k0 += BK) {
    __syncthreads();
    #pragma unroll
    for (int p = 0; p < 4; ++p) {
      gl2lds16(pA[p], dA[p]); pA[p] += BK;
      gl2lds16(pB[p], dB[p]); pB[p] += BK;
    }
    __syncthreads();
    #pragma unroll
    for (int s = 0; s < 2; ++s) {
      short8_t af[4], bfr[4];
      #pragma unroll
      for (int i = 0; i < 4; ++i) {
        int ar = wm + i * 16 + ml;
        af[i]  = *(const short8_t*)&lsA[ar * BK + (((s * 4 + kq) ^ ((ar >> 1) & 7)) * 8)];
        int br = wn + i * 16 + ml;
        bfr[i] = *(const short8_t*)&lsB[br * BK + (((s * 4 + kq) ^ ((br >> 1) & 7)) * 8)];
      }
      #pragma unroll
      for (int i = 0; i < 4; ++i)
        #pragma unroll
        for (int j = 0; j < 4; ++j)
          acc[i][j] = __builtin_amdgcn_mfma_f32_16x16x32_bf16(
              FragArg{af[i]}, FragArg{bfr[j]}, acc[i][j], 0, 0, 0);
    }
  }

  #pragma unroll
  for (int i = 0; i < 4; ++i) {
    int rb = wm + i * 16 + kq * 4;
    #pragma unroll
    for (int r2 = 0; r2 < 4; ++r2) {
      int row = rb + r2;
      if (m0 + row < cnt) {
        float v = s_v[row];
        size_t ro = (size_t)(base + m0 + row) * HD + n0;
        #pragma unroll
        for (int j = 0; j < 4; ++j) {
          float z = acc[i][j][r2];
          float val = v * (z / (1.0f + __expf(-z)));   // gate_w * silu(z)
          hbuf[ro + wn + j * 16 + ml] = f2b(val);
        }
      }
    }
  }
}

// ------------------- GEMM2: o_slot = h_rows @ WprojT -----------------------
__global__ __launch_bounds__(256) void gemm2_kernel(
    const unsigned short* __restrict__ hbuf, const unsigned short* __restrict__ wpjp,
    const int* __restrict__ g_counts, const int* __restrict__ g_base,
    unsigned short* __restrict__ oslot)
{
  int id = blockIdx.x;
  int e = id & 7;
  int r = id >> 3;
  int nt = r & 7;                  // CD/128 = 8 n-tiles, fastest
  int mt = r >> 3;                 // [0, MTILES)

  int cnt = g_counts[e];
  int m0 = mt * 128;
  if (m0 >= cnt) return;
  int base = g_base[e];
  int n0 = nt * 128;

  __shared__ __align__(16) unsigned short lsA[128 * BK];
  __shared__ __align__(16) unsigned short lsB[128 * BK];

  int t = threadIdx.x;
  int lane = t & 63, wv = t >> 6;
  int subrow = lane >> 3, kc = lane & 7;
  // Padded rows over-read past hbuf into oslot region (inside d_ws); their
  // stores are guarded below.
  const unsigned short* pA[4]; const unsigned short* pB[4];
  unsigned short* dA[4]; unsigned short* dB[4];
  #pragma unroll
  for (int p = 0; p < 4; ++p) {
    int rr = p * 32 + wv * 8 + subrow;
    int gc = kc ^ ((rr >> 1) & 7);
    pA[p] = hbuf + ((size_t)(base + m0 + rr)) * HD + gc * 8;
    pB[p] = wpjp + ((size_t)e * CD + n0 + rr) * HD + gc * 8;
    dA[p] = &lsA[(p * 32 + wv * 8) * BK];
    dB[p] = &lsB[(p * 32 + wv * 8) * BK];
  }

  int wm = (wv & 1) * 64, wn = (wv >> 1) * 64;
  int ml = lane & 15, kq = lane >> 4;

  f32x4_t acc[4][4];
  #pragma unroll
  for (int i = 0; i < 4; ++i)
    #pragma unroll
    for (int j = 0; j < 4; ++j) acc[i][j] = (f32x4_t){0.f, 0.f, 0.f, 0.f};

  for (int k0 = 0; k0 < HD; k0 += BK) {
    __syncthreads();
    #pragma unroll
    for (int p = 0; p < 4; ++p) {
      gl2lds16(pA[p], dA[p]); pA[p] += BK;
      gl2lds16(pB[p], dB[p]); pB[p] += BK;
    }
    __syncthreads();
    #pragma unroll
    for (int s = 0; s < 2; ++s) {
      short8_t af[4], bfr[4];
      #pragma unroll
      for (int i = 0; i < 4; ++i) {
        int ar = wm + i * 16 + ml;
        af[i]  = *(const short8_t*)&lsA[ar * BK + (((s * 4 + kq) ^ ((ar >> 1) & 7)) * 8)];
        int br = wn + i * 16 + ml;
        bfr[i] = *(const short8_t*)&lsB[br * BK + (((s * 4 + kq) ^ ((br >> 1) & 7)) * 8)];
      }
      #pragma unroll
      for (int i = 0; i < 4; ++i)
        #pragma unroll
        for (int j = 0; j < 4; ++j)
          acc[i][j] = __builtin_amdgcn_mfma_f32_16x16x32_bf16(
              FragArg{af[i]}, FragArg{bfr[j]}, acc[i][j], 0, 0, 0);
    }
  }

  #pragma unroll
  for (int i = 0; i < 4; ++i) {
    int rb = wm + i * 16 + kq * 4;
    #pragma unroll
    for (int r2 = 0; r2 < 4; ++r2) {
      int row = rb + r2;
      if (m0 + row < cnt) {
        size_t ro = (size_t)(base + m0 + row) * CD + n0;
        #pragma unroll
        for (int j = 0; j < 4; ++j)
          oslot[ro + wn + j * 16 + ml] = f2b(acc[i][j][r2]);
      }
    }
  }
}

// ----------- combine: out[t] = fp32(oslot[s0]) + fp32(oslot[s1]) -----------
__global__ __launch_bounds__(256) void combine_kernel(
    const unsigned short* __restrict__ oslot, const int* __restrict__ slot_of,
    float* __restrict__ out)
{
  int gid = blockIdx.x * 256 + threadIdx.x;
  int tk = gid >> 7;               // 128 chunks of 8 per token
  int ch = (gid & 127) * 8;
  int s0 = slot_of[tk * 2], s1 = slot_of[tk * 2 + 1];
  short8_t a = *(const short8_t*)(oslot + (size_t)s0 * CD + ch);
  short8_t b = *(const short8_t*)(oslot + (size_t)s1 * CD + ch);
  float* op = out + (size_t)tk * CD + ch;
  float4 o0, o1;
  o0.x = b2f((unsigned short)a[0]) + b2f((unsigned short)b[0]);
  o0.y = b2f((unsigned short)a[1]) + b2f((unsigned short)b[1]);
  o0.z = b2f((unsigned short)a[2]) + b2f((unsigned short)b[2]);
  o0.w = b2f((unsigned short)a[3]) + b2f((unsigned short)b[3]);
  o1.x = b2f((unsigned short)a[4]) + b2f((unsigned short)b[4]);
  o1.y = b2f((unsigned short)a[5]) + b2f((unsigned short)b[5]);
  o1.z = b2f((unsigned short)a[6]) + b2f((unsigned short)b[6]);
  o1.w = b2f((unsigned short)a[7]) + b2f((unsigned short)b[7]);
  *(float4*)op = o0;
  *(float4*)(op + 4) = o1;
}

// ---------------------------------------------------------------------------
extern "C" void kernel_launch(void* const* d_in, const int* in_sizes, int n_in,
                              void* d_out, int out_size, void* d_ws, size_t ws_size,
                              hipStream_t stream)
{
  const float* x   = (const float*)d_in[0];
  const float* wg  = (const float*)d_in[1];
  const float* wfc = (const float*)d_in[2];
  const float* wpj = (const float*)d_in[3];
  float* out = (float*)d_out;

  // workspace carve-up (~185 MB). hbuf precedes oslot so padded-tile A
  // over-reads in gemm2 stay inside d_ws.
  char* w = (char*)d_ws;
  unsigned short* wfcp  = (unsigned short*)w; w += (size_t)NE * HD * CD * 2;  // 33.5 MB
  unsigned short* wpjp  = (unsigned short*)w; w += (size_t)NE * CD * HD * 2;  // 33.5 MB
  unsigned short* xb    = (unsigned short*)w; w += (size_t)NTOK * CD * 2;     // 16.8 MB
  unsigned short* hbuf  = (unsigned short*)w; w += (size_t)NSLOT * HD * 2;    // 67.1 MB
  unsigned short* oslot = (unsigned short*)w; w += (size_t)NSLOT * CD * 2;    // 33.5 MB
  int*   tok_e      = (int*)w;   w += NSLOT * 4;
  float* tok_v      = (float*)w; w += NSLOT * 4;
  int*   slot_of    = (int*)w;   w += NSLOT * 4;
  int*   bucket_tok = (int*)w;   w += NSLOT * 4;
  float* bucket_v   = (float*)w; w += NSLOT * 4;
  int*   g_counts   = (int*)w;   w += NE * 4;   // contiguous with g_cursor:
  int*   g_cursor   = (int*)w;   w += NE * 4;   // one 64B memset covers both
  int*   g_base     = (int*)w;   w += 256;

  hipMemsetAsync(g_counts, 0, 2 * NE * sizeof(int), stream);
  prep_kernel<<<GATE_BLOCKS + PACK_BLOCKS, 256, 0, stream>>>(
      x, wg, wfc, xb, wfcp, tok_e, tok_v, g_counts);
  scatter_kernel<<<NSLOT / 256, 256, 0, stream>>>(
      tok_e, tok_v, g_counts, g_cursor, g_base, bucket_tok, bucket_v, slot_of);
  gemm1_kernel<<<PACK_BLOCKS + (HD / 128) * MTILES * NE, 256, 0, stream>>>(
      xb, wfcp, wpj, wpjp, g_counts, g_base, bucket_tok, bucket_v, hbuf);
  gemm2_kernel<<<(CD / 128) * MTILES * NE, 256, 0, stream>>>(
      hbuf, wpjp, g_counts, g_base, oslot);
  combine_kernel<<<(NTOK * CD / 8) / 256, 256, 0, stream>>>(oslot, slot_of, out);
}